// Round 4
// baseline (2667.230 us; speedup 1.0000x reference)
//
#include <hip/hip_runtime.h>

#define NS 0.2f  // leaky_relu negative slope

// ===================== CSR construction =====================
__global__ void k_deg(const int* __restrict__ dst, int* degi, int E){
  int stride = gridDim.x * blockDim.x;
  for(int e = blockIdx.x * blockDim.x + threadIdx.x; e < E; e += stride)
    atomicAdd(&degi[dst[e]], 1);
}

__device__ __forceinline__ int wave_iscan(int v, int lane){
  #pragma unroll
  for(int o = 1; o < 64; o <<= 1){
    int t = __shfl_up(v, o);
    if(lane >= o) v += t;
  }
  return v;
}

__global__ void k_scan(const int* __restrict__ deg, int* __restrict__ rowoff, int n){
  __shared__ int wsum[16];
  __shared__ int carry_s;
  const int lane = threadIdx.x & 63;
  const int w = threadIdx.x >> 6;
  if(threadIdx.x == 0) carry_s = 0;
  __syncthreads();
  for(int base = 0; base < n; base += 1024){
    int idx = base + (int)threadIdx.x;
    int v = (idx < n) ? deg[idx] : 0;
    int inc = wave_iscan(v, lane);
    if(lane == 63) wsum[w] = inc;
    __syncthreads();
    if(w == 0){
      int s = (lane < 16) ? wsum[lane] : 0;
      s = wave_iscan(s, lane);
      if(lane < 16) wsum[lane] = s;
    }
    __syncthreads();
    int woff = (w > 0) ? wsum[w - 1] : 0;
    int total = wsum[15];
    if(idx < n) rowoff[idx] = carry_s + woff + inc - v;
    __syncthreads();
    if(threadIdx.x == 0) carry_s += total;
    __syncthreads();
  }
  if(threadIdx.x == 0) rowoff[n] = carry_s;
}

__global__ void k_fill(const int* __restrict__ dst, int* pos, int* eidx, int E){
  int stride = gridDim.x * blockDim.x;
  for(int e = blockIdx.x * blockDim.x + threadIdx.x; e < E; e += stride){
    int slot = atomicAdd(&pos[dst[e]], 1);
    eidx[slot] = e;
  }
}

// ===================== tiled GEMM: C = A @ W^T + b =====================
#define BM 64
#define BN 64
#define BK 16
__global__ __launch_bounds__(256) void k_gemm(
    const float* __restrict__ A, const float* __restrict__ W,
    const float* __restrict__ b, float* __restrict__ C,
    int n, int K, int M, int dorelu)
{
  __shared__ float As[BM][BK + 1];
  __shared__ float Bs[BN][BK + 1];
  const int bi = blockIdx.x * BM;
  const int bj = blockIdx.y * BN;
  const int tid = threadIdx.x;
  const int tr = tid / 16, tc = tid % 16;
  float acc[4][4] = {};
  for(int k0 = 0; k0 < K; k0 += BK){
    for(int l = tid; l < BM * BK; l += 256){
      int r = l / BK, c = l % BK;
      int gr = bi + r, gc = k0 + c;
      As[r][c] = (gr < n && gc < K) ? A[(long)gr * K + gc] : 0.0f;
    }
    for(int l = tid; l < BN * BK; l += 256){
      int r = l / BK, c = l % BK;
      int gr = bj + r, gc = k0 + c;
      Bs[r][c] = (gr < M && gc < K) ? W[(long)gr * K + gc] : 0.0f;
    }
    __syncthreads();
    #pragma unroll
    for(int kk = 0; kk < BK; ++kk){
      float av[4], bv[4];
      #pragma unroll
      for(int r = 0; r < 4; r++) av[r] = As[tr * 4 + r][kk];
      #pragma unroll
      for(int c = 0; c < 4; c++) bv[c] = Bs[tc * 4 + c][kk];
      #pragma unroll
      for(int r = 0; r < 4; r++)
        #pragma unroll
        for(int c = 0; c < 4; c++) acc[r][c] += av[r] * bv[c];
    }
    __syncthreads();
  }
  for(int r = 0; r < 4; r++){
    int gr = bi + tr * 4 + r;
    if(gr >= n) continue;
    for(int c = 0; c < 4; c++){
      int gc = bj + tc * 4 + c;
      if(gc >= M) continue;
      float val = acc[r][c] + b[gc];
      C[(long)gr * M + gc] = dorelu ? fmaxf(val, 0.0f) : val;
    }
  }
}

static void gemm_launch(const float* A, const float* W, const float* b, float* C,
                        int n, int K, int M, int relu, hipStream_t s){
  dim3 grid((n + BM - 1) / BM, (M + BN - 1) / BN);
  k_gemm<<<grid, 256, 0, s>>>(A, W, b, C, n, K, M, relu);
}

// ===================== edge logits: one G-LANE GROUP per edge, CSR order =====================
// Group loads the full xl[src]/xr[dst] rows with single float4 instructions
// (contiguous 400/800 B -> full-line fetches), ea broadcast via LDS.
// Writes packed {logit, src_bits} at the CSR position -> coalesced, and
// consumed sequentially by k_gat_agg.
template<int G, int FMAX>
__global__ __launch_bounds__(256) void k_edge_logits(
    const float* __restrict__ xl, const float* __restrict__ xr,
    const float* __restrict__ ea,
    const int* __restrict__ src, const int* __restrict__ dst,
    const int* __restrict__ eidx,
    const float* __restrict__ We, const float* __restrict__ att,
    float2* __restrict__ lw, int E, int F)
{
  constexpr int NG = 256 / G;            // edge-groups per block
  __shared__ float4 sWe[FMAX * 5];       // F rows padded to 20 floats
  __shared__ float  sAtt[FMAX];
  __shared__ float  sEa[NG][18];
  const int tid = threadIdx.x;
  for(int idx = tid; idx < F * 5; idx += 256){
    int f = idx / 5, q = idx % 5, k0 = q * 4;
    float4 v;
    v.x = (k0 + 0 < 18) ? We[f * 18 + k0 + 0] : 0.0f;
    v.y = (k0 + 1 < 18) ? We[f * 18 + k0 + 1] : 0.0f;
    v.z = (k0 + 2 < 18) ? We[f * 18 + k0 + 2] : 0.0f;
    v.w = (k0 + 3 < 18) ? We[f * 18 + k0 + 3] : 0.0f;
    sWe[idx] = v;
  }
  for(int f = tid; f < F; f += 256) sAtt[f] = att[f];

  const int g  = tid / G;
  const int gl = tid % G;
  const long p = (long)blockIdx.x * NG + g;   // CSR position
  int e = 0, s = 0, d = 0;
  const bool ok = (p < (long)E);
  if(ok){
    e = eidx[p];                // same addr across group -> broadcast
    s = src[e];
    d = dst[e];
    if(gl < 18) sEa[g][gl] = ea[(long)e * 18 + gl];
  }
  __syncthreads();
  if(!ok) return;

  float acc = 0.0f;
  if(gl * 4 < F){
    float4 xa = *(const float4*)(xl + (long)s * F + gl * 4);
    float4 xb = *(const float4*)(xr + (long)d * F + gl * 4);
    float eav[20];
    #pragma unroll
    for(int k = 0; k < 18; k++) eav[k] = sEa[g][k];
    eav[18] = 0.0f; eav[19] = 0.0f;
    float tv[4] = {xa.x + xb.x, xa.y + xb.y, xa.z + xb.z, xa.w + xb.w};
    #pragma unroll
    for(int c = 0; c < 4; c++){
      int f = gl * 4 + c;
      float t = tv[c];
      #pragma unroll
      for(int q = 0; q < 5; q++){
        float4 wq = sWe[f * 5 + q];
        t = fmaf(wq.x, eav[4 * q + 0], t);
        t = fmaf(wq.y, eav[4 * q + 1], t);
        t = fmaf(wq.z, eav[4 * q + 2], t);
        t = fmaf(wq.w, eav[4 * q + 3], t);
      }
      t = (t > 0.0f) ? t : NS * t;
      acc = fmaf(sAtt[f], t, acc);
    }
  }
  #pragma unroll
  for(int o = G / 2; o; o >>= 1) acc += __shfl_xor(acc, o);
  if(gl == 0) lw[p] = make_float2(acc, __int_as_float(s));
}

// ===================== node softmax + aggregate: one WAVE per node =====================
#define CH 128
template<int JMAX>
__global__ __launch_bounds__(256) void k_gat_agg(
    const float* __restrict__ xl, const float* __restrict__ xr,
    const float* __restrict__ ea,
    const int* __restrict__ rowoff, const int* __restrict__ eidx,
    const float2* __restrict__ lw,
    const float* __restrict__ We, const float* __restrict__ att,
    const float* __restrict__ bias, float* __restrict__ out,
    int n, int F, int dorelu)
{
  const int lane = threadIdx.x & 63;
  const int wid  = threadIdx.x >> 6;
  __shared__ float  s_eam[4][20];
  __shared__ float2 s_ws[4][CH];   // {weight, src bits}
  const int i = blockIdx.x * 4 + wid;
  if(i >= n) return;          // wave-uniform exit; no __syncthreads below
  const int r0 = rowoff[i], r1 = rowoff[i + 1];
  const int deg = r1 - r0;

  // ---- ea_mean for self-loop ----
  if(lane < 20){
    float ssum = 0.0f;
    if(lane < 18)
      for(int p = r0; p < r1; ++p) ssum += ea[(long)eidx[p] * 18 + lane];
    s_eam[wid][lane] = (lane < 18) ? ssum / fmaxf((float)deg, 1.0f) : 0.0f;
  }

  // ---- self logit (feature-parallel) + cache xl[i] ----
  float selfl = 0.0f;
  float xiv[JMAX];
  #pragma unroll
  for(int j = 0; j < JMAX; ++j){
    int f = lane + j * 64;
    xiv[j] = 0.0f;
    if(f < F){
      float xv = xl[(long)i * F + f];
      xiv[j] = xv;
      float t = xv + xr[(long)i * F + f];
      const float* w = We + f * 18;
      #pragma unroll
      for(int k = 0; k < 18; k++) t = fmaf(w[k], s_eam[wid][k], t);
      t = (t > 0.0f) ? t : NS * t;
      selfl = fmaf(att[f], t, selfl);
    }
  }
  #pragma unroll
  for(int o = 32; o; o >>= 1) selfl += __shfl_xor(selfl, o);

  // ---- online softmax init with self-loop ----
  float m = selfl, denom = 1.0f;
  float acc[JMAX];
  #pragma unroll
  for(int j = 0; j < JMAX; ++j) acc[j] = xiv[j];

  // ---- chunks of incident edges ----
  for(int c0 = 0; c0 < deg; c0 += CH){
    int cn = min(CH, deg - c0);
    // coalesced stream of {logit, src} in CSR order
    float lmax = -3.4e38f;
    for(int q = lane; q < cn; q += 64){
      float2 ws = lw[r0 + c0 + q];
      s_ws[wid][q] = ws;
      lmax = fmaxf(lmax, ws.x);
    }
    #pragma unroll
    for(int o = 32; o; o >>= 1) lmax = fmaxf(lmax, __shfl_xor(lmax, o));
    float newm = fmaxf(m, lmax);
    float scale = expf(m - newm);
    denom *= scale;
    #pragma unroll
    for(int j = 0; j < JMAX; ++j) acc[j] *= scale;
    m = newm;
    float psum = 0.0f;
    for(int q = lane; q < cn; q += 64){
      float2 ws = s_ws[wid][q];
      float w = expf(ws.x - m);
      s_ws[wid][q].x = w;
      psum += w;
    }
    #pragma unroll
    for(int o = 32; o; o >>= 1) psum += __shfl_xor(psum, o);
    denom += psum;
    for(int p = 0; p < cn; ++p){
      float2 ws = s_ws[wid][p];
      float w = ws.x;
      int s = __float_as_int(ws.y);
      const float* xs = xl + (long)s * F;
      #pragma unroll
      for(int j = 0; j < JMAX; ++j){
        int f = lane + j * 64;
        if(f < F) acc[j] = fmaf(w, xs[f], acc[j]);
      }
    }
  }

  // ---- write ----
  float inv = 1.0f / denom;
  #pragma unroll
  for(int j = 0; j < JMAX; ++j){
    int f = lane + j * 64;
    if(f < F){
      float o = acc[j] * inv + bias[f];
      out[(long)i * F + f] = dorelu ? fmaxf(o, 0.0f) : o;
    }
  }
}

// ===================== rule pooling (rule_batch sorted) =====================
__global__ void k_rule_starts(const int* __restrict__ rb, int* starts, int NR, int R){
  int r = blockIdx.x * blockDim.x + threadIdx.x;
  if(r > R) return;
  if(r == R){ starts[R] = NR; return; }
  int lo = 0, hi = NR;
  while(lo < hi){ int mid = (lo + hi) >> 1; if(rb[mid] < r) lo = mid + 1; else hi = mid; }
  starts[r] = lo;
}

__global__ void k_pool_rules(const float* __restrict__ h, const int* __restrict__ starts,
                             float* __restrict__ y, int R, int F){
  long idx = (long)blockIdx.x * blockDim.x + threadIdx.x;
  long total = (long)R * F;
  if(idx >= total) return;
  int r = (int)(idx / F);
  int f = (int)(idx % F);
  int s0 = starts[r], s1 = starts[r + 1];
  float a = 0.0f;
  for(int i = s0; i < s1; i++) a += h[(long)i * F + f];
  y[idx] = a / fmaxf((float)(s1 - s0), 1.0f);
}

// ===================== global mean + bilinear =====================
__global__ void k_pool_all(const float* __restrict__ g, float* xp, long total4, int F){
  __shared__ float s[128];
  for(int j = threadIdx.x; j < F; j += blockDim.x) s[j] = 0.0f;
  __syncthreads();
  long stride = (long)gridDim.x * blockDim.x;
  const float4* g4 = (const float4*)g;
  for(long idx = (long)blockIdx.x * blockDim.x + threadIdx.x; idx < total4; idx += stride){
    float4 v = g4[idx];
    long base = idx * 4;
    atomicAdd(&s[(int)((base + 0) % F)], v.x);
    atomicAdd(&s[(int)((base + 1) % F)], v.y);
    atomicAdd(&s[(int)((base + 2) % F)], v.z);
    atomicAdd(&s[(int)((base + 3) % F)], v.w);
  }
  __syncthreads();
  for(int j = threadIdx.x; j < F; j += blockDim.x){
    float v = s[j];
    if(v != 0.0f) atomicAdd(&xp[j], v);
  }
}

__global__ void k_bil_v(const float* __restrict__ xp, const float* __restrict__ Wb,
                        float* v, float inv_n){
  int e = threadIdx.x;
  if(e < 100){
    float a = 0.0f;
    for(int d = 0; d < 100; d++) a += xp[d] * Wb[d * 100 + e];
    v[e] = a * inv_n;
  }
}

__global__ void k_bil_out(const float* __restrict__ v, const float* __restrict__ y,
                          const float* __restrict__ bilb, float* out, int R){
  int r = blockIdx.x * blockDim.x + threadIdx.x;
  if(r < R){
    float a = 0.0f;
    const float* yr = y + (long)r * 100;
    for(int e = 0; e < 100; e++) a += v[e] * yr[e];
    out[r] = a + bilb[0];
  }
}

// ------------------------------------------------------------------
static inline int nblk(long n){
  long b = (n + 255) / 256;
  if(b > 20480) b = 20480;
  if(b < 1) b = 1;
  return (int)b;
}

struct GatParams { const float *Wl,*bl,*Wr,*br,*We,*att,*b; };

static void run_gatv2(const float* x, int fin, int fout, int n,
                      const int* src, const int* dst, const float* ea, int E,
                      GatParams P, float* out, int dorelu,
                      float* xl, float* xr, float2* lw,
                      const int* rowoff, const int* eidx, hipStream_t stream){
  gemm_launch(x, P.Wl, P.bl, xl, n, fin, fout, 0, stream);
  gemm_launch(x, P.Wr, P.br, xr, n, fin, fout, 0, stream);
  if(fout <= 128){
    // 32 lanes per edge, 8 edge-groups per block
    int grid = (E + 7) / 8;
    k_edge_logits<32, 128><<<grid, 256, 0, stream>>>(xl, xr, ea, src, dst, eidx,
                                                     P.We, P.att, lw, E, fout);
    k_gat_agg<2><<<(n + 3) / 4, 256, 0, stream>>>(xl, xr, ea, rowoff, eidx, lw,
                                                  P.We, P.att, P.b, out, n, fout, dorelu);
  } else {
    // 64 lanes per edge, 4 edge-groups per block
    int grid = (E + 3) / 4;
    k_edge_logits<64, 256><<<grid, 256, 0, stream>>>(xl, xr, ea, src, dst, eidx,
                                                     P.We, P.att, lw, E, fout);
    k_gat_agg<4><<<(n + 3) / 4, 256, 0, stream>>>(xl, xr, ea, rowoff, eidx, lw,
                                                  P.We, P.att, P.b, out, n, fout, dorelu);
  }
}

extern "C" void kernel_launch(void* const* d_in, const int* in_sizes, int n_in,
                              void* d_out, int out_size, void* d_ws, size_t ws_size,
                              hipStream_t stream){
  const float* x   = (const float*)d_in[0];
  const float* ea  = (const float*)d_in[1];
  const float* rx  = (const float*)d_in[2];
  const float* rea = (const float*)d_in[3];
  GatParams g0{ (const float*)d_in[4],  (const float*)d_in[5],  (const float*)d_in[6],
                (const float*)d_in[7],  (const float*)d_in[8],  (const float*)d_in[9],
                (const float*)d_in[10] };
  GatParams g1{ (const float*)d_in[11], (const float*)d_in[12], (const float*)d_in[13],
                (const float*)d_in[14], (const float*)d_in[15], (const float*)d_in[16],
                (const float*)d_in[17] };
  GatParams g2{ (const float*)d_in[18], (const float*)d_in[19], (const float*)d_in[20],
                (const float*)d_in[21], (const float*)d_in[22], (const float*)d_in[23],
                (const float*)d_in[24] };
  const float* lin_W = (const float*)d_in[25]; const float* lin_b = (const float*)d_in[26];
  const float* f1_W  = (const float*)d_in[27]; const float* f1_b  = (const float*)d_in[28];
  const float* f2_W  = (const float*)d_in[29]; const float* f2_b  = (const float*)d_in[30];
  const float* f3_W  = (const float*)d_in[31]; const float* f3_b  = (const float*)d_in[32];
  const float* bilW  = (const float*)d_in[33]; const float* bilb  = (const float*)d_in[34];
  const int* ei  = (const int*)d_in[35];
  const int* rei = (const int*)d_in[37];
  const int* rb  = (const int*)d_in[38];

  const int N  = in_sizes[0] / 16;
  const int E  = in_sizes[1] / 18;
  const int NR = in_sizes[2] / 16;
  const int ER = in_sizes[3] / 18;
  const int R  = out_size;

  float* Wf = (float*)d_ws;
  size_t off = 0;
  // round allocations to even float counts so float2 views stay 8-B aligned
  auto alloc  = [&](size_t nf){ nf = (nf + 1) & ~(size_t)1; float* p = Wf + off; off += nf; return p; };
  auto alloci = [&](size_t ni){ ni = (ni + 1) & ~(size_t)1; int* p = (int*)(Wf + off); off += ni; return p; };

  // persistent head
  float* y0 = alloc((size_t)R * 400);
  float* y1 = alloc((size_t)R * 200);
  float* y2 = alloc((size_t)R * 100);
  float* y3 = alloc((size_t)R * 100);
  float* xp = alloc(128);
  float* v  = alloc(128);
  int* starts = alloci(R + 1);
  const size_t arena = off;

  // ================= rule path =================
  {
    off = arena;
    float* h1 = alloc((size_t)NR * 100);
    float* h2 = alloc((size_t)NR * 200);
    float* xl = alloc((size_t)NR * 200);
    float* xr = alloc((size_t)NR * 200);
    float2* lw = (float2*)alloc((size_t)ER * 2);
    int* rowoff = alloci(NR + 1);
    int* degi   = alloci(NR);
    int* pos    = alloci(NR);
    int* eidx   = alloci(ER);
    const int* rsrc = rei; const int* rdst = rei + ER;

    hipMemsetAsync(degi, 0, (size_t)NR * 4, stream);
    k_deg<<<nblk(ER), 256, 0, stream>>>(rdst, degi, ER);
    k_scan<<<1, 1024, 0, stream>>>(degi, rowoff, NR);
    hipMemcpyAsync(pos, rowoff, (size_t)NR * 4, hipMemcpyDeviceToDevice, stream);
    k_fill<<<nblk(ER), 256, 0, stream>>>(rdst, pos, eidx, ER);

    run_gatv2(rx, 16, 100, NR, rsrc, rdst, rea, ER, g1, h1, 1,
              xl, xr, lw, rowoff, eidx, stream);
    run_gatv2(h1, 100, 200, NR, rsrc, rdst, rea, ER, g2, h2, 1,
              xl, xr, lw, rowoff, eidx, stream);

    float* hlin = xl;  // NR*400 floats (xl+xr contiguous)
    gemm_launch(h2, lin_W, lin_b, hlin, NR, 200, 400, 0, stream);

    k_rule_starts<<<(R + 256) / 256, 256, 0, stream>>>(rb, starts, NR, R);
    k_pool_rules<<<nblk((long)R * 400), 256, 0, stream>>>(hlin, starts, y0, R, 400);

    gemm_launch(y0, f1_W, f1_b, y1, R, 400, 200, 1, stream);
    gemm_launch(y1, f2_W, f2_b, y2, R, 200, 100, 1, stream);
    gemm_launch(y2, f3_W, f3_b, y3, R, 100, 100, 0, stream);
  }

  // ================= data path =================
  {
    off = arena;
    float* g  = alloc((size_t)N * 100);
    float* xl = alloc((size_t)N * 100);
    float* xr = alloc((size_t)N * 100);
    float2* lw = (float2*)alloc((size_t)E * 2);
    int* rowoff = alloci((size_t)N + 1);
    int* degi   = alloci(N);
    int* pos    = alloci(N);
    int* eidx   = alloci(E);
    const int* srcp = ei; const int* dstp = ei + E;

    hipMemsetAsync(degi, 0, (size_t)N * 4, stream);
    k_deg<<<nblk(E), 256, 0, stream>>>(dstp, degi, E);
    k_scan<<<1, 1024, 0, stream>>>(degi, rowoff, N);
    hipMemcpyAsync(pos, rowoff, (size_t)N * 4, hipMemcpyDeviceToDevice, stream);
    k_fill<<<nblk(E), 256, 0, stream>>>(dstp, pos, eidx, E);

    run_gatv2(x, 16, 100, N, srcp, dstp, ea, E, g0, g, 0,
              xl, xr, lw, rowoff, eidx, stream);

    hipMemsetAsync(xp, 0, 128 * 4, stream);
    k_pool_all<<<nblk((long)N * 25), 256, 0, stream>>>(g, xp, (long)N * 25, 100);
    k_bil_v<<<1, 128, 0, stream>>>(xp, bilW, v, 1.0f / (float)N);
    k_bil_out<<<(R + 127) / 128, 128, 0, stream>>>(v, y3, bilb, (float*)d_out, R);
  }
}

// Round 5
// 1882.463 us; speedup vs baseline: 1.4169x; 1.4169x over previous
//
#include <hip/hip_runtime.h>

#define NS 0.2f  // leaky_relu negative slope

// ===================== CSR construction =====================
__global__ void k_deg(const int* __restrict__ dst, int* degi, int E){
  int stride = gridDim.x * blockDim.x;
  for(int e = blockIdx.x * blockDim.x + threadIdx.x; e < E; e += stride)
    atomicAdd(&degi[dst[e]], 1);
}

__device__ __forceinline__ int wave_iscan(int v, int lane){
  #pragma unroll
  for(int o = 1; o < 64; o <<= 1){
    int t = __shfl_up(v, o);
    if(lane >= o) v += t;
  }
  return v;
}

__global__ void k_scan(const int* __restrict__ deg, int* __restrict__ rowoff, int n){
  __shared__ int wsum[16];
  __shared__ int carry_s;
  const int lane = threadIdx.x & 63;
  const int w = threadIdx.x >> 6;
  if(threadIdx.x == 0) carry_s = 0;
  __syncthreads();
  for(int base = 0; base < n; base += 1024){
    int idx = base + (int)threadIdx.x;
    int v = (idx < n) ? deg[idx] : 0;
    int inc = wave_iscan(v, lane);
    if(lane == 63) wsum[w] = inc;
    __syncthreads();
    if(w == 0){
      int s = (lane < 16) ? wsum[lane] : 0;
      s = wave_iscan(s, lane);
      if(lane < 16) wsum[lane] = s;
    }
    __syncthreads();
    int woff = (w > 0) ? wsum[w - 1] : 0;
    int total = wsum[15];
    if(idx < n) rowoff[idx] = carry_s + woff + inc - v;
    __syncthreads();
    if(threadIdx.x == 0) carry_s += total;
    __syncthreads();
  }
  if(threadIdx.x == 0) rowoff[n] = carry_s;
}

__global__ void k_fill(const int* __restrict__ dst, int* pos, int* eidx, int E){
  int stride = gridDim.x * blockDim.x;
  for(int e = blockIdx.x * blockDim.x + threadIdx.x; e < E; e += stride){
    int slot = atomicAdd(&pos[dst[e]], 1);
    eidx[slot] = e;
  }
}

// ===================== tiled GEMM: C = A @ W^T + b =====================
#define BM 64
#define BN 64
#define BK 16
__global__ __launch_bounds__(256) void k_gemm(
    const float* __restrict__ A, const float* __restrict__ W,
    const float* __restrict__ b, float* __restrict__ C,
    int n, int K, int M, int dorelu)
{
  __shared__ float As[BM][BK + 1];
  __shared__ float Bs[BN][BK + 1];
  const int bi = blockIdx.x * BM;
  const int bj = blockIdx.y * BN;
  const int tid = threadIdx.x;
  const int tr = tid / 16, tc = tid % 16;
  float acc[4][4] = {};
  for(int k0 = 0; k0 < K; k0 += BK){
    for(int l = tid; l < BM * BK; l += 256){
      int r = l / BK, c = l % BK;
      int gr = bi + r, gc = k0 + c;
      As[r][c] = (gr < n && gc < K) ? A[(long)gr * K + gc] : 0.0f;
    }
    for(int l = tid; l < BN * BK; l += 256){
      int r = l / BK, c = l % BK;
      int gr = bj + r, gc = k0 + c;
      Bs[r][c] = (gr < M && gc < K) ? W[(long)gr * K + gc] : 0.0f;
    }
    __syncthreads();
    #pragma unroll
    for(int kk = 0; kk < BK; ++kk){
      float av[4], bv[4];
      #pragma unroll
      for(int r = 0; r < 4; r++) av[r] = As[tr * 4 + r][kk];
      #pragma unroll
      for(int c = 0; c < 4; c++) bv[c] = Bs[tc * 4 + c][kk];
      #pragma unroll
      for(int r = 0; r < 4; r++)
        #pragma unroll
        for(int c = 0; c < 4; c++) acc[r][c] += av[r] * bv[c];
    }
    __syncthreads();
  }
  for(int r = 0; r < 4; r++){
    int gr = bi + tr * 4 + r;
    if(gr >= n) continue;
    for(int c = 0; c < 4; c++){
      int gc = bj + tc * 4 + c;
      if(gc >= M) continue;
      float val = acc[r][c] + b[gc];
      C[(long)gr * M + gc] = dorelu ? fmaxf(val, 0.0f) : val;
    }
  }
}

static void gemm_launch(const float* A, const float* W, const float* b, float* C,
                        int n, int K, int M, int relu, hipStream_t s){
  dim3 grid((n + BM - 1) / BM, (M + BN - 1) / BN);
  k_gemm<<<grid, 256, 0, s>>>(A, W, b, C, n, K, M, relu);
}

// ===================== edge logits: one G-LANE GROUP per edge, CSR order =====================
// Full xl[src]/xr[dst] rows loaded with single float4 instructions (contiguous,
// full-line fetches). We staged in LDS TRANSPOSED [k][f] so each lane's float4
// read is contiguous across lanes -> zero bank conflicts (R4 had 6.5e8 from the
// [f][k] layout's stride-20 reads). Writes packed {logit, src} at CSR position.
template<int G, int FMAX>
__global__ __launch_bounds__(256) void k_edge_logits(
    const float* __restrict__ xl, const float* __restrict__ xr,
    const float* __restrict__ ea,
    const int* __restrict__ src, const int* __restrict__ dst,
    const int* __restrict__ eidx,
    const float* __restrict__ We, const float* __restrict__ att,
    float2* __restrict__ lw, int E, int F)
{
  constexpr int NG = 256 / G;            // edge-groups per block
  __shared__ float sWeT[18 * FMAX];      // transposed: sWeT[k*F + f] = We[f*18 + k]
  __shared__ float sAtt[FMAX];
  __shared__ float sEa[NG][18];
  const int tid = threadIdx.x;
  for(int idx = tid; idx < F * 18; idx += 256){
    int f = idx / 18, k = idx % 18;      // coalesced global read
    sWeT[k * F + f] = We[idx];
  }
  for(int f = tid; f < F; f += 256) sAtt[f] = att[f];

  const int g  = tid / G;
  const int gl = tid % G;
  const long p = (long)blockIdx.x * NG + g;   // CSR position
  int e = 0, s = 0, d = 0;
  const bool ok = (p < (long)E);
  if(ok){
    e = eidx[p];                // same addr across group -> broadcast
    s = src[e];
    d = dst[e];
    if(gl < 18) sEa[g][gl] = ea[(long)e * 18 + gl];
  }
  __syncthreads();
  if(!ok) return;

  float acc = 0.0f;
  if(gl * 4 < F){
    float4 xa = *(const float4*)(xl + (long)s * F + gl * 4);
    float4 xb = *(const float4*)(xr + (long)d * F + gl * 4);
    float eav[18];
    #pragma unroll
    for(int k = 0; k < 18; k++) eav[k] = sEa[g][k];
    float t0 = xa.x + xb.x, t1 = xa.y + xb.y, t2 = xa.z + xb.z, t3 = xa.w + xb.w;
    #pragma unroll
    for(int k = 0; k < 18; k++){
      float4 w = *(const float4*)&sWeT[k * F + gl * 4];  // contiguous across lanes
      t0 = fmaf(w.x, eav[k], t0);
      t1 = fmaf(w.y, eav[k], t1);
      t2 = fmaf(w.z, eav[k], t2);
      t3 = fmaf(w.w, eav[k], t3);
    }
    t0 = (t0 > 0.0f) ? t0 : NS * t0;
    t1 = (t1 > 0.0f) ? t1 : NS * t1;
    t2 = (t2 > 0.0f) ? t2 : NS * t2;
    t3 = (t3 > 0.0f) ? t3 : NS * t3;
    float4 av = *(const float4*)&sAtt[gl * 4];           // contiguous across lanes
    acc = av.x * t0 + av.y * t1 + av.z * t2 + av.w * t3;
  }
  #pragma unroll
  for(int o = G / 2; o; o >>= 1) acc += __shfl_xor(acc, o);
  if(gl == 0) lw[p] = make_float2(acc, __int_as_float(s));
}

// ===================== node softmax + aggregate: one WAVE per node =====================
#define CH 128
template<int JMAX>
__global__ __launch_bounds__(256) void k_gat_agg(
    const float* __restrict__ xl, const float* __restrict__ xr,
    const float* __restrict__ ea,
    const int* __restrict__ rowoff, const int* __restrict__ eidx,
    const float2* __restrict__ lw,
    const float* __restrict__ We, const float* __restrict__ att,
    const float* __restrict__ bias, float* __restrict__ out,
    int n, int F, int dorelu)
{
  const int lane = threadIdx.x & 63;
  const int wid  = threadIdx.x >> 6;
  __shared__ float  s_eam[4][20];
  __shared__ float2 s_ws[4][CH];   // {weight, src bits}
  const int i = blockIdx.x * 4 + wid;
  if(i >= n) return;          // wave-uniform exit; no __syncthreads below
  const int r0 = rowoff[i], r1 = rowoff[i + 1];
  const int deg = r1 - r0;

  // ---- ea_mean for self-loop ----
  if(lane < 20){
    float ssum = 0.0f;
    if(lane < 18)
      for(int p = r0; p < r1; ++p) ssum += ea[(long)eidx[p] * 18 + lane];
    s_eam[wid][lane] = (lane < 18) ? ssum / fmaxf((float)deg, 1.0f) : 0.0f;
  }

  // ---- self logit (feature-parallel) + cache xl[i] ----
  float selfl = 0.0f;
  float xiv[JMAX];
  #pragma unroll
  for(int j = 0; j < JMAX; ++j){
    int f = lane + j * 64;
    xiv[j] = 0.0f;
    if(f < F){
      float xv = xl[(long)i * F + f];
      xiv[j] = xv;
      float t = xv + xr[(long)i * F + f];
      const float* w = We + f * 18;
      #pragma unroll
      for(int k = 0; k < 18; k++) t = fmaf(w[k], s_eam[wid][k], t);
      t = (t > 0.0f) ? t : NS * t;
      selfl = fmaf(att[f], t, selfl);
    }
  }
  #pragma unroll
  for(int o = 32; o; o >>= 1) selfl += __shfl_xor(selfl, o);

  // ---- online softmax init with self-loop ----
  float m = selfl, denom = 1.0f;
  float acc[JMAX];
  #pragma unroll
  for(int j = 0; j < JMAX; ++j) acc[j] = xiv[j];

  // ---- chunks of incident edges ----
  for(int c0 = 0; c0 < deg; c0 += CH){
    int cn = min(CH, deg - c0);
    // coalesced stream of {logit, src} in CSR order
    float lmax = -3.4e38f;
    for(int q = lane; q < cn; q += 64){
      float2 ws = lw[r0 + c0 + q];
      s_ws[wid][q] = ws;
      lmax = fmaxf(lmax, ws.x);
    }
    #pragma unroll
    for(int o = 32; o; o >>= 1) lmax = fmaxf(lmax, __shfl_xor(lmax, o));
    float newm = fmaxf(m, lmax);
    float scale = expf(m - newm);
    denom *= scale;
    #pragma unroll
    for(int j = 0; j < JMAX; ++j) acc[j] *= scale;
    m = newm;
    float psum = 0.0f;
    for(int q = lane; q < cn; q += 64){
      float2 ws = s_ws[wid][q];
      float w = expf(ws.x - m);
      s_ws[wid][q].x = w;
      psum += w;
    }
    #pragma unroll
    for(int o = 32; o; o >>= 1) psum += __shfl_xor(psum, o);
    denom += psum;
    for(int p = 0; p < cn; ++p){
      float2 ws = s_ws[wid][p];
      float w = ws.x;
      int s = __float_as_int(ws.y);
      const float* xs = xl + (long)s * F;
      #pragma unroll
      for(int j = 0; j < JMAX; ++j){
        int f = lane + j * 64;
        if(f < F) acc[j] = fmaf(w, xs[f], acc[j]);
      }
    }
  }

  // ---- write ----
  float inv = 1.0f / denom;
  #pragma unroll
  for(int j = 0; j < JMAX; ++j){
    int f = lane + j * 64;
    if(f < F){
      float o = acc[j] * inv + bias[f];
      out[(long)i * F + f] = dorelu ? fmaxf(o, 0.0f) : o;
    }
  }
}

// ===================== rule pooling (rule_batch sorted) =====================
__global__ void k_rule_starts(const int* __restrict__ rb, int* starts, int NR, int R){
  int r = blockIdx.x * blockDim.x + threadIdx.x;
  if(r > R) return;
  if(r == R){ starts[R] = NR; return; }
  int lo = 0, hi = NR;
  while(lo < hi){ int mid = (lo + hi) >> 1; if(rb[mid] < r) lo = mid + 1; else hi = mid; }
  starts[r] = lo;
}

__global__ void k_pool_rules(const float* __restrict__ h, const int* __restrict__ starts,
                             float* __restrict__ y, int R, int F){
  long idx = (long)blockIdx.x * blockDim.x + threadIdx.x;
  long total = (long)R * F;
  if(idx >= total) return;
  int r = (int)(idx / F);
  int f = (int)(idx % F);
  int s0 = starts[r], s1 = starts[r + 1];
  float a = 0.0f;
  for(int i = s0; i < s1; i++) a += h[(long)i * F + f];
  y[idx] = a / fmaxf((float)(s1 - s0), 1.0f);
}

// ===================== global mean + bilinear =====================
__global__ void k_pool_all(const float* __restrict__ g, float* xp, long total4, int F){
  __shared__ float s[128];
  for(int j = threadIdx.x; j < F; j += blockDim.x) s[j] = 0.0f;
  __syncthreads();
  long stride = (long)gridDim.x * blockDim.x;
  const float4* g4 = (const float4*)g;
  for(long idx = (long)blockIdx.x * blockDim.x + threadIdx.x; idx < total4; idx += stride){
    float4 v = g4[idx];
    long base = idx * 4;
    atomicAdd(&s[(int)((base + 0) % F)], v.x);
    atomicAdd(&s[(int)((base + 1) % F)], v.y);
    atomicAdd(&s[(int)((base + 2) % F)], v.z);
    atomicAdd(&s[(int)((base + 3) % F)], v.w);
  }
  __syncthreads();
  for(int j = threadIdx.x; j < F; j += blockDim.x){
    float v = s[j];
    if(v != 0.0f) atomicAdd(&xp[j], v);
  }
}

__global__ void k_bil_v(const float* __restrict__ xp, const float* __restrict__ Wb,
                        float* v, float inv_n){
  int e = threadIdx.x;
  if(e < 100){
    float a = 0.0f;
    for(int d = 0; d < 100; d++) a += xp[d] * Wb[d * 100 + e];
    v[e] = a * inv_n;
  }
}

__global__ void k_bil_out(const float* __restrict__ v, const float* __restrict__ y,
                          const float* __restrict__ bilb, float* out, int R){
  int r = blockIdx.x * blockDim.x + threadIdx.x;
  if(r < R){
    float a = 0.0f;
    const float* yr = y + (long)r * 100;
    for(int e = 0; e < 100; e++) a += v[e] * yr[e];
    out[r] = a + bilb[0];
  }
}

// ------------------------------------------------------------------
static inline int nblk(long n){
  long b = (n + 255) / 256;
  if(b > 20480) b = 20480;
  if(b < 1) b = 1;
  return (int)b;
}

struct GatParams { const float *Wl,*bl,*Wr,*br,*We,*att,*b; };

static void run_gatv2(const float* x, int fin, int fout, int n,
                      const int* src, const int* dst, const float* ea, int E,
                      GatParams P, float* out, int dorelu,
                      float* xl, float* xr, float2* lw,
                      const int* rowoff, const int* eidx, hipStream_t stream){
  gemm_launch(x, P.Wl, P.bl, xl, n, fin, fout, 0, stream);
  gemm_launch(x, P.Wr, P.br, xr, n, fin, fout, 0, stream);
  if(fout <= 128){
    // 32 lanes per edge, 8 edge-groups per block
    int grid = (E + 7) / 8;
    k_edge_logits<32, 128><<<grid, 256, 0, stream>>>(xl, xr, ea, src, dst, eidx,
                                                     P.We, P.att, lw, E, fout);
    k_gat_agg<2><<<(n + 3) / 4, 256, 0, stream>>>(xl, xr, ea, rowoff, eidx, lw,
                                                  P.We, P.att, P.b, out, n, fout, dorelu);
  } else {
    // 64 lanes per edge, 4 edge-groups per block
    int grid = (E + 3) / 4;
    k_edge_logits<64, 256><<<grid, 256, 0, stream>>>(xl, xr, ea, src, dst, eidx,
                                                     P.We, P.att, lw, E, fout);
    k_gat_agg<4><<<(n + 3) / 4, 256, 0, stream>>>(xl, xr, ea, rowoff, eidx, lw,
                                                  P.We, P.att, P.b, out, n, fout, dorelu);
  }
}

extern "C" void kernel_launch(void* const* d_in, const int* in_sizes, int n_in,
                              void* d_out, int out_size, void* d_ws, size_t ws_size,
                              hipStream_t stream){
  const float* x   = (const float*)d_in[0];
  const float* ea  = (const float*)d_in[1];
  const float* rx  = (const float*)d_in[2];
  const float* rea = (const float*)d_in[3];
  GatParams g0{ (const float*)d_in[4],  (const float*)d_in[5],  (const float*)d_in[6],
                (const float*)d_in[7],  (const float*)d_in[8],  (const float*)d_in[9],
                (const float*)d_in[10] };
  GatParams g1{ (const float*)d_in[11], (const float*)d_in[12], (const float*)d_in[13],
                (const float*)d_in[14], (const float*)d_in[15], (const float*)d_in[16],
                (const float*)d_in[17] };
  GatParams g2{ (const float*)d_in[18], (const float*)d_in[19], (const float*)d_in[20],
                (const float*)d_in[21], (const float*)d_in[22], (const float*)d_in[23],
                (const float*)d_in[24] };
  const float* lin_W = (const float*)d_in[25]; const float* lin_b = (const float*)d_in[26];
  const float* f1_W  = (const float*)d_in[27]; const float* f1_b  = (const float*)d_in[28];
  const float* f2_W  = (const float*)d_in[29]; const float* f2_b  = (const float*)d_in[30];
  const float* f3_W  = (const float*)d_in[31]; const float* f3_b  = (const float*)d_in[32];
  const float* bilW  = (const float*)d_in[33]; const float* bilb  = (const float*)d_in[34];
  const int* ei  = (const int*)d_in[35];
  const int* rei = (const int*)d_in[37];
  const int* rb  = (const int*)d_in[38];

  const int N  = in_sizes[0] / 16;
  const int E  = in_sizes[1] / 18;
  const int NR = in_sizes[2] / 16;
  const int ER = in_sizes[3] / 18;
  const int R  = out_size;

  float* Wf = (float*)d_ws;
  size_t off = 0;
  // round allocations to even float counts so float2 views stay 8-B aligned
  auto alloc  = [&](size_t nf){ nf = (nf + 1) & ~(size_t)1; float* p = Wf + off; off += nf; return p; };
  auto alloci = [&](size_t ni){ ni = (ni + 1) & ~(size_t)1; int* p = (int*)(Wf + off); off += ni; return p; };

  // persistent head
  float* y0 = alloc((size_t)R * 400);
  float* y1 = alloc((size_t)R * 200);
  float* y2 = alloc((size_t)R * 100);
  float* y3 = alloc((size_t)R * 100);
  float* xp = alloc(128);
  float* v  = alloc(128);
  int* starts = alloci(R + 1);
  const size_t arena = off;

  // ================= rule path =================
  {
    off = arena;
    float* h1 = alloc((size_t)NR * 100);
    float* h2 = alloc((size_t)NR * 200);
    float* xl = alloc((size_t)NR * 200);
    float* xr = alloc((size_t)NR * 200);
    float2* lw = (float2*)alloc((size_t)ER * 2);
    int* rowoff = alloci(NR + 1);
    int* degi   = alloci(NR);
    int* pos    = alloci(NR);
    int* eidx   = alloci(ER);
    const int* rsrc = rei; const int* rdst = rei + ER;

    hipMemsetAsync(degi, 0, (size_t)NR * 4, stream);
    k_deg<<<nblk(ER), 256, 0, stream>>>(rdst, degi, ER);
    k_scan<<<1, 1024, 0, stream>>>(degi, rowoff, NR);
    hipMemcpyAsync(pos, rowoff, (size_t)NR * 4, hipMemcpyDeviceToDevice, stream);
    k_fill<<<nblk(ER), 256, 0, stream>>>(rdst, pos, eidx, ER);

    run_gatv2(rx, 16, 100, NR, rsrc, rdst, rea, ER, g1, h1, 1,
              xl, xr, lw, rowoff, eidx, stream);
    run_gatv2(h1, 100, 200, NR, rsrc, rdst, rea, ER, g2, h2, 1,
              xl, xr, lw, rowoff, eidx, stream);

    float* hlin = xl;  // NR*400 floats (xl+xr contiguous)
    gemm_launch(h2, lin_W, lin_b, hlin, NR, 200, 400, 0, stream);

    k_rule_starts<<<(R + 256) / 256, 256, 0, stream>>>(rb, starts, NR, R);
    k_pool_rules<<<nblk((long)R * 400), 256, 0, stream>>>(hlin, starts, y0, R, 400);

    gemm_launch(y0, f1_W, f1_b, y1, R, 400, 200, 1, stream);
    gemm_launch(y1, f2_W, f2_b, y2, R, 200, 100, 1, stream);
    gemm_launch(y2, f3_W, f3_b, y3, R, 100, 100, 0, stream);
  }

  // ================= data path =================
  {
    off = arena;
    float* g  = alloc((size_t)N * 100);
    float* xl = alloc((size_t)N * 100);
    float* xr = alloc((size_t)N * 100);
    float2* lw = (float2*)alloc((size_t)E * 2);
    int* rowoff = alloci((size_t)N + 1);
    int* degi   = alloci(N);
    int* pos    = alloci(N);
    int* eidx   = alloci(E);
    const int* srcp = ei; const int* dstp = ei + E;

    hipMemsetAsync(degi, 0, (size_t)N * 4, stream);
    k_deg<<<nblk(E), 256, 0, stream>>>(dstp, degi, E);
    k_scan<<<1, 1024, 0, stream>>>(degi, rowoff, N);
    hipMemcpyAsync(pos, rowoff, (size_t)N * 4, hipMemcpyDeviceToDevice, stream);
    k_fill<<<nblk(E), 256, 0, stream>>>(dstp, pos, eidx, E);

    run_gatv2(x, 16, 100, N, srcp, dstp, ea, E, g0, g, 0,
              xl, xr, lw, rowoff, eidx, stream);

    hipMemsetAsync(xp, 0, 128 * 4, stream);
    k_pool_all<<<nblk((long)N * 25), 256, 0, stream>>>(g, xp, (long)N * 25, 100);
    k_bil_v<<<1, 128, 0, stream>>>(xp, bilW, v, 1.0f / (float)N);
    k_bil_out<<<(R + 127) / 128, 128, 0, stream>>>(v, y3, bilb, (float*)d_out, R);
  }
}

// Round 6
// 1437.114 us; speedup vs baseline: 1.8560x; 1.3099x over previous
//
#include <hip/hip_runtime.h>

#define NS 0.2f  // leaky_relu negative slope

// ===================== CSR construction =====================
__global__ void k_deg(const int* __restrict__ dst, int* degi, int E){
  int stride = gridDim.x * blockDim.x;
  for(int e = blockIdx.x * blockDim.x + threadIdx.x; e < E; e += stride)
    atomicAdd(&degi[dst[e]], 1);
}

__device__ __forceinline__ int wave_iscan(int v, int lane){
  #pragma unroll
  for(int o = 1; o < 64; o <<= 1){
    int t = __shfl_up(v, o);
    if(lane >= o) v += t;
  }
  return v;
}

__global__ void k_scan(const int* __restrict__ deg, int* __restrict__ rowoff, int n){
  __shared__ int wsum[16];
  __shared__ int carry_s;
  const int lane = threadIdx.x & 63;
  const int w = threadIdx.x >> 6;
  if(threadIdx.x == 0) carry_s = 0;
  __syncthreads();
  for(int base = 0; base < n; base += 1024){
    int idx = base + (int)threadIdx.x;
    int v = (idx < n) ? deg[idx] : 0;
    int inc = wave_iscan(v, lane);
    if(lane == 63) wsum[w] = inc;
    __syncthreads();
    if(w == 0){
      int s = (lane < 16) ? wsum[lane] : 0;
      s = wave_iscan(s, lane);
      if(lane < 16) wsum[lane] = s;
    }
    __syncthreads();
    int woff = (w > 0) ? wsum[w - 1] : 0;
    int total = wsum[15];
    if(idx < n) rowoff[idx] = carry_s + woff + inc - v;
    __syncthreads();
    if(threadIdx.x == 0) carry_s += total;
    __syncthreads();
  }
  if(threadIdx.x == 0) rowoff[n] = carry_s;
}

__global__ void k_fill(const int* __restrict__ dst, int* pos, int* eidx, int E){
  int stride = gridDim.x * blockDim.x;
  for(int e = blockIdx.x * blockDim.x + threadIdx.x; e < E; e += stride){
    int slot = atomicAdd(&pos[dst[e]], 1);
    eidx[slot] = e;
  }
}

// ===================== tiled GEMM: C = A @ W^T + b =====================
#define BM 64
#define BN 64
#define BK 16
__global__ __launch_bounds__(256) void k_gemm(
    const float* __restrict__ A, const float* __restrict__ W,
    const float* __restrict__ b, float* __restrict__ C,
    int n, int K, int M, int dorelu)
{
  __shared__ float As[BM][BK + 1];
  __shared__ float Bs[BN][BK + 1];
  const int bi = blockIdx.x * BM;
  const int bj = blockIdx.y * BN;
  const int tid = threadIdx.x;
  const int tr = tid / 16, tc = tid % 16;
  float acc[4][4] = {};
  for(int k0 = 0; k0 < K; k0 += BK){
    for(int l = tid; l < BM * BK; l += 256){
      int r = l / BK, c = l % BK;
      int gr = bi + r, gc = k0 + c;
      As[r][c] = (gr < n && gc < K) ? A[(long)gr * K + gc] : 0.0f;
    }
    for(int l = tid; l < BN * BK; l += 256){
      int r = l / BK, c = l % BK;
      int gr = bj + r, gc = k0 + c;
      Bs[r][c] = (gr < M && gc < K) ? W[(long)gr * K + gc] : 0.0f;
    }
    __syncthreads();
    #pragma unroll
    for(int kk = 0; kk < BK; ++kk){
      float av[4], bv[4];
      #pragma unroll
      for(int r = 0; r < 4; r++) av[r] = As[tr * 4 + r][kk];
      #pragma unroll
      for(int c = 0; c < 4; c++) bv[c] = Bs[tc * 4 + c][kk];
      #pragma unroll
      for(int r = 0; r < 4; r++)
        #pragma unroll
        for(int c = 0; c < 4; c++) acc[r][c] += av[r] * bv[c];
    }
    __syncthreads();
  }
  for(int r = 0; r < 4; r++){
    int gr = bi + tr * 4 + r;
    if(gr >= n) continue;
    for(int c = 0; c < 4; c++){
      int gc = bj + tc * 4 + c;
      if(gc >= M) continue;
      float val = acc[r][c] + b[gc];
      C[(long)gr * M + gc] = dorelu ? fmaxf(val, 0.0f) : val;
    }
  }
}

static void gemm_launch(const float* A, const float* W, const float* b, float* C,
                        int n, int K, int M, int relu, hipStream_t s){
  dim3 grid((n + BM - 1) / BM, (M + BN - 1) / BN);
  k_gemm<<<grid, 256, 0, s>>>(A, W, b, C, n, K, M, relu);
}

__device__ __forceinline__ float lkrelu(float t){ return (t > 0.0f) ? t : NS * t; }

// ===================== edge logits: G-lane group x NE=4 edges, persistent blocks =====================
// We/att staged in LDS ONCE per block (grid-stride loop). Per group-iteration,
// 4 edges' ea rows are packed as sEa[k] = (e0,e1,e2,e3), so the k-loop costs
// 2 LDS float4 reads (1 lane-varying WeT quad + 1 group-uniform ea quad) per
// k for 4 edges -> 4.5 ds_read/edge vs 18 in R5. Group-private LDS is written
// and read by the same wave -> no barriers in the loop.
template<int G, int F>
__global__ __launch_bounds__(256) void k_edge_logits(
    const float* __restrict__ xl, const float* __restrict__ xr,
    const float* __restrict__ ea,
    const int* __restrict__ src, const int* __restrict__ dst,
    const int* __restrict__ eidx,
    const float* __restrict__ We, const float* __restrict__ att,
    float2* __restrict__ lw, int E)
{
  constexpr int NG = 256 / G;       // groups per block
  constexpr int NE = 4;             // edges per group-iteration
  constexpr int FQ = F / 4;         // float4s per feature row
  __shared__ float4 sWeT[18 * FQ];  // [k][f4], transposed
  __shared__ float4 sAtt[FQ];
  __shared__ float4 sEa[NG][18];    // [k] -> (ea_e0, ea_e1, ea_e2, ea_e3)
  __shared__ int    sIdx[NG][3][NE];// [0]=e, [1]=src, [2]=dst

  const int tid = threadIdx.x;
  for(int idx = tid; idx < F * 18; idx += 256){
    int f = idx / 18, k = idx % 18;            // coalesced global read
    ((float*)sWeT)[k * F + f] = We[idx];
  }
  for(int f = tid; f < F; f += 256) ((float*)sAtt)[f] = att[f];
  __syncthreads();

  const int g  = tid / G;
  const int gl = tid % G;
  const bool act = (gl * 4 < F);
  const int glc = act ? gl : 0;
  const long step = (long)gridDim.x * (NG * NE);

  for(long base = (long)blockIdx.x * (NG * NE); base < (long)E; base += step){
    const long pb = base + (long)g * NE;
    // --- stage edge ids for this group's 4 CSR positions ---
    if(gl < NE){
      long p = pb + gl;
      int e = -1, s = 0, d = 0;
      if(p < (long)E){ e = eidx[p]; s = src[e]; d = dst[e]; }
      sIdx[g][0][gl] = e; sIdx[g][1][gl] = s; sIdx[g][2][gl] = d;
    }
    // --- stage 4 ea rows, packed k-major with ne in float4 lanes ---
    #pragma unroll
    for(int t = 0; t < (18 * NE + G - 1) / G; ++t){
      int u = t * G + gl;
      if(u < 18 * NE){
        int ne = u & 3, k = u >> 2;
        int e = sIdx[g][0][ne];
        ((float*)&sEa[g][k])[ne] = (e >= 0) ? ea[(long)e * 18 + k] : 0.0f;
      }
    }
    int4 sv = *(const int4*)&sIdx[g][1][0];
    int4 dv = *(const int4*)&sIdx[g][2][0];
    // --- gather full xl/xr rows (contiguous float4 per lane) ---
    float4 a0 = *(const float4*)(xl + (long)sv.x * F + glc * 4);
    float4 b0 = *(const float4*)(xr + (long)dv.x * F + glc * 4);
    float4 a1 = *(const float4*)(xl + (long)sv.y * F + glc * 4);
    float4 b1 = *(const float4*)(xr + (long)dv.y * F + glc * 4);
    float4 a2 = *(const float4*)(xl + (long)sv.z * F + glc * 4);
    float4 b2 = *(const float4*)(xr + (long)dv.z * F + glc * 4);
    float4 a3 = *(const float4*)(xl + (long)sv.w * F + glc * 4);
    float4 b3 = *(const float4*)(xr + (long)dv.w * F + glc * 4);
    float4 t0 = make_float4(a0.x + b0.x, a0.y + b0.y, a0.z + b0.z, a0.w + b0.w);
    float4 t1 = make_float4(a1.x + b1.x, a1.y + b1.y, a1.z + b1.z, a1.w + b1.w);
    float4 t2 = make_float4(a2.x + b2.x, a2.y + b2.y, a2.z + b2.z, a2.w + b2.w);
    float4 t3 = make_float4(a3.x + b3.x, a3.y + b3.y, a3.z + b3.z, a3.w + b3.w);
    // --- We @ ea for 4 edges: 2 LDS reads + 16 FMA per k ---
    #pragma unroll
    for(int k = 0; k < 18; ++k){
      float4 w  = sWeT[k * FQ + glc];
      float4 eq = sEa[g][k];
      t0.x = fmaf(w.x, eq.x, t0.x); t0.y = fmaf(w.y, eq.x, t0.y);
      t0.z = fmaf(w.z, eq.x, t0.z); t0.w = fmaf(w.w, eq.x, t0.w);
      t1.x = fmaf(w.x, eq.y, t1.x); t1.y = fmaf(w.y, eq.y, t1.y);
      t1.z = fmaf(w.z, eq.y, t1.z); t1.w = fmaf(w.w, eq.y, t1.w);
      t2.x = fmaf(w.x, eq.z, t2.x); t2.y = fmaf(w.y, eq.z, t2.y);
      t2.z = fmaf(w.z, eq.z, t2.z); t2.w = fmaf(w.w, eq.z, t2.w);
      t3.x = fmaf(w.x, eq.w, t3.x); t3.y = fmaf(w.y, eq.w, t3.y);
      t3.z = fmaf(w.z, eq.w, t3.z); t3.w = fmaf(w.w, eq.w, t3.w);
    }
    // --- leaky + att dot ---
    float4 av = sAtt[glc];
    float r0 = 0, r1 = 0, r2 = 0, r3 = 0;
    if(act){
      r0 = av.x * lkrelu(t0.x) + av.y * lkrelu(t0.y) + av.z * lkrelu(t0.z) + av.w * lkrelu(t0.w);
      r1 = av.x * lkrelu(t1.x) + av.y * lkrelu(t1.y) + av.z * lkrelu(t1.z) + av.w * lkrelu(t1.w);
      r2 = av.x * lkrelu(t2.x) + av.y * lkrelu(t2.y) + av.z * lkrelu(t2.z) + av.w * lkrelu(t2.w);
      r3 = av.x * lkrelu(t3.x) + av.y * lkrelu(t3.y) + av.z * lkrelu(t3.z) + av.w * lkrelu(t3.w);
    }
    #pragma unroll
    for(int o = G / 2; o; o >>= 1){
      r0 += __shfl_xor(r0, o);
      r1 += __shfl_xor(r1, o);
      r2 += __shfl_xor(r2, o);
      r3 += __shfl_xor(r3, o);
    }
    if(gl == 0 && pb + 0 < (long)E) lw[pb + 0] = make_float2(r0, __int_as_float(sv.x));
    if(gl == 1 && pb + 1 < (long)E) lw[pb + 1] = make_float2(r1, __int_as_float(sv.y));
    if(gl == 2 && pb + 2 < (long)E) lw[pb + 2] = make_float2(r2, __int_as_float(sv.z));
    if(gl == 3 && pb + 3 < (long)E) lw[pb + 3] = make_float2(r3, __int_as_float(sv.w));
  }
}

// ===================== node softmax + aggregate: one WAVE per node =====================
#define CH 128
template<int JMAX>
__global__ __launch_bounds__(256) void k_gat_agg(
    const float* __restrict__ xl, const float* __restrict__ xr,
    const float* __restrict__ ea,
    const int* __restrict__ rowoff, const int* __restrict__ eidx,
    const float2* __restrict__ lw,
    const float* __restrict__ We, const float* __restrict__ att,
    const float* __restrict__ bias, float* __restrict__ out,
    int n, int F, int dorelu)
{
  const int lane = threadIdx.x & 63;
  const int wid  = threadIdx.x >> 6;
  __shared__ float  s_eam[4][20];
  __shared__ float2 s_ws[4][CH];   // {weight, src bits}
  const int i = blockIdx.x * 4 + wid;
  if(i >= n) return;          // wave-uniform exit; no __syncthreads below
  const int r0 = rowoff[i], r1 = rowoff[i + 1];
  const int deg = r1 - r0;

  // ---- ea_mean for self-loop ----
  if(lane < 20){
    float ssum = 0.0f;
    if(lane < 18)
      for(int p = r0; p < r1; ++p) ssum += ea[(long)eidx[p] * 18 + lane];
    s_eam[wid][lane] = (lane < 18) ? ssum / fmaxf((float)deg, 1.0f) : 0.0f;
  }

  // ---- self logit (feature-parallel) + cache xl[i] ----
  float selfl = 0.0f;
  float xiv[JMAX];
  #pragma unroll
  for(int j = 0; j < JMAX; ++j){
    int f = lane + j * 64;
    xiv[j] = 0.0f;
    if(f < F){
      float xv = xl[(long)i * F + f];
      xiv[j] = xv;
      float t = xv + xr[(long)i * F + f];
      const float* w = We + f * 18;
      #pragma unroll
      for(int k = 0; k < 18; k++) t = fmaf(w[k], s_eam[wid][k], t);
      t = (t > 0.0f) ? t : NS * t;
      selfl = fmaf(att[f], t, selfl);
    }
  }
  #pragma unroll
  for(int o = 32; o; o >>= 1) selfl += __shfl_xor(selfl, o);

  // ---- online softmax init with self-loop ----
  float m = selfl, denom = 1.0f;
  float acc[JMAX];
  #pragma unroll
  for(int j = 0; j < JMAX; ++j) acc[j] = xiv[j];

  // ---- chunks of incident edges ----
  for(int c0 = 0; c0 < deg; c0 += CH){
    int cn = min(CH, deg - c0);
    // coalesced stream of {logit, src} in CSR order
    float lmax = -3.4e38f;
    for(int q = lane; q < cn; q += 64){
      float2 ws = lw[r0 + c0 + q];
      s_ws[wid][q] = ws;
      lmax = fmaxf(lmax, ws.x);
    }
    #pragma unroll
    for(int o = 32; o; o >>= 1) lmax = fmaxf(lmax, __shfl_xor(lmax, o));
    float newm = fmaxf(m, lmax);
    float scale = expf(m - newm);
    denom *= scale;
    #pragma unroll
    for(int j = 0; j < JMAX; ++j) acc[j] *= scale;
    m = newm;
    float psum = 0.0f;
    for(int q = lane; q < cn; q += 64){
      float2 ws = s_ws[wid][q];
      float w = expf(ws.x - m);
      s_ws[wid][q].x = w;
      psum += w;
    }
    #pragma unroll
    for(int o = 32; o; o >>= 1) psum += __shfl_xor(psum, o);
    denom += psum;
    for(int p = 0; p < cn; ++p){
      float2 ws = s_ws[wid][p];
      float w = ws.x;
      int s = __float_as_int(ws.y);
      const float* xs = xl + (long)s * F;
      #pragma unroll
      for(int j = 0; j < JMAX; ++j){
        int f = lane + j * 64;
        if(f < F) acc[j] = fmaf(w, xs[f], acc[j]);
      }
    }
  }

  // ---- write ----
  float inv = 1.0f / denom;
  #pragma unroll
  for(int j = 0; j < JMAX; ++j){
    int f = lane + j * 64;
    if(f < F){
      float o = acc[j] * inv + bias[f];
      out[(long)i * F + f] = dorelu ? fmaxf(o, 0.0f) : o;
    }
  }
}

// ===================== rule pooling (rule_batch sorted) =====================
__global__ void k_rule_starts(const int* __restrict__ rb, int* starts, int NR, int R){
  int r = blockIdx.x * blockDim.x + threadIdx.x;
  if(r > R) return;
  if(r == R){ starts[R] = NR; return; }
  int lo = 0, hi = NR;
  while(lo < hi){ int mid = (lo + hi) >> 1; if(rb[mid] < r) lo = mid + 1; else hi = mid; }
  starts[r] = lo;
}

__global__ void k_pool_rules(const float* __restrict__ h, const int* __restrict__ starts,
                             float* __restrict__ y, int R, int F){
  long idx = (long)blockIdx.x * blockDim.x + threadIdx.x;
  long total = (long)R * F;
  if(idx >= total) return;
  int r = (int)(idx / F);
  int f = (int)(idx % F);
  int s0 = starts[r], s1 = starts[r + 1];
  float a = 0.0f;
  for(int i = s0; i < s1; i++) a += h[(long)i * F + f];
  y[idx] = a / fmaxf((float)(s1 - s0), 1.0f);
}

// ===================== global mean + bilinear =====================
__global__ void k_pool_all(const float* __restrict__ g, float* xp, long total4, int F){
  __shared__ float s[128];
  for(int j = threadIdx.x; j < F; j += blockDim.x) s[j] = 0.0f;
  __syncthreads();
  long stride = (long)gridDim.x * blockDim.x;
  const float4* g4 = (const float4*)g;
  for(long idx = (long)blockIdx.x * blockDim.x + threadIdx.x; idx < total4; idx += stride){
    float4 v = g4[idx];
    long base = idx * 4;
    atomicAdd(&s[(int)((base + 0) % F)], v.x);
    atomicAdd(&s[(int)((base + 1) % F)], v.y);
    atomicAdd(&s[(int)((base + 2) % F)], v.z);
    atomicAdd(&s[(int)((base + 3) % F)], v.w);
  }
  __syncthreads();
  for(int j = threadIdx.x; j < F; j += blockDim.x){
    float v = s[j];
    if(v != 0.0f) atomicAdd(&xp[j], v);
  }
}

__global__ void k_bil_v(const float* __restrict__ xp, const float* __restrict__ Wb,
                        float* v, float inv_n){
  int e = threadIdx.x;
  if(e < 100){
    float a = 0.0f;
    for(int d = 0; d < 100; d++) a += xp[d] * Wb[d * 100 + e];
    v[e] = a * inv_n;
  }
}

__global__ void k_bil_out(const float* __restrict__ v, const float* __restrict__ y,
                          const float* __restrict__ bilb, float* out, int R){
  int r = blockIdx.x * blockDim.x + threadIdx.x;
  if(r < R){
    float a = 0.0f;
    const float* yr = y + (long)r * 100;
    for(int e = 0; e < 100; e++) a += v[e] * yr[e];
    out[r] = a + bilb[0];
  }
}

// ------------------------------------------------------------------
static inline int nblk(long n){
  long b = (n + 255) / 256;
  if(b > 20480) b = 20480;
  if(b < 1) b = 1;
  return (int)b;
}

struct GatParams { const float *Wl,*bl,*Wr,*br,*We,*att,*b; };

template<int G, int F>
static void edge_logits_launch(const float* xl, const float* xr, const float* ea,
                               const int* src, const int* dst, const int* eidx,
                               const float* We, const float* att, float2* lw,
                               int E, hipStream_t stream){
  const int epb = (256 / G) * 4;   // edges per block-iteration
  long nb = ((long)E + epb - 1) / epb;
  int grid = (int)(nb < 2048 ? nb : 2048);
  k_edge_logits<G, F><<<grid, 256, 0, stream>>>(xl, xr, ea, src, dst, eidx, We, att, lw, E);
}

static void run_gatv2(const float* x, int fin, int fout, int n,
                      const int* src, const int* dst, const float* ea, int E,
                      GatParams P, float* out, int dorelu,
                      float* xl, float* xr, float2* lw,
                      const int* rowoff, const int* eidx, hipStream_t stream){
  gemm_launch(x, P.Wl, P.bl, xl, n, fin, fout, 0, stream);
  gemm_launch(x, P.Wr, P.br, xr, n, fin, fout, 0, stream);
  if(fout == 100){
    edge_logits_launch<32, 100>(xl, xr, ea, src, dst, eidx, P.We, P.att, lw, E, stream);
    k_gat_agg<2><<<(n + 3) / 4, 256, 0, stream>>>(xl, xr, ea, rowoff, eidx, lw,
                                                  P.We, P.att, P.b, out, n, fout, dorelu);
  } else {
    edge_logits_launch<64, 200>(xl, xr, ea, src, dst, eidx, P.We, P.att, lw, E, stream);
    k_gat_agg<4><<<(n + 3) / 4, 256, 0, stream>>>(xl, xr, ea, rowoff, eidx, lw,
                                                  P.We, P.att, P.b, out, n, fout, dorelu);
  }
}

extern "C" void kernel_launch(void* const* d_in, const int* in_sizes, int n_in,
                              void* d_out, int out_size, void* d_ws, size_t ws_size,
                              hipStream_t stream){
  const float* x   = (const float*)d_in[0];
  const float* ea  = (const float*)d_in[1];
  const float* rx  = (const float*)d_in[2];
  const float* rea = (const float*)d_in[3];
  GatParams g0{ (const float*)d_in[4],  (const float*)d_in[5],  (const float*)d_in[6],
                (const float*)d_in[7],  (const float*)d_in[8],  (const float*)d_in[9],
                (const float*)d_in[10] };
  GatParams g1{ (const float*)d_in[11], (const float*)d_in[12], (const float*)d_in[13],
                (const float*)d_in[14], (const float*)d_in[15], (const float*)d_in[16],
                (const float*)d_in[17] };
  GatParams g2{ (const float*)d_in[18], (const float*)d_in[19], (const float*)d_in[20],
                (const float*)d_in[21], (const float*)d_in[22], (const float*)d_in[23],
                (const float*)d_in[24] };
  const float* lin_W = (const float*)d_in[25]; const float* lin_b = (const float*)d_in[26];
  const float* f1_W  = (const float*)d_in[27]; const float* f1_b  = (const float*)d_in[28];
  const float* f2_W  = (const float*)d_in[29]; const float* f2_b  = (const float*)d_in[30];
  const float* f3_W  = (const float*)d_in[31]; const float* f3_b  = (const float*)d_in[32];
  const float* bilW  = (const float*)d_in[33]; const float* bilb  = (const float*)d_in[34];
  const int* ei  = (const int*)d_in[35];
  const int* rei = (const int*)d_in[37];
  const int* rb  = (const int*)d_in[38];

  const int N  = in_sizes[0] / 16;
  const int E  = in_sizes[1] / 18;
  const int NR = in_sizes[2] / 16;
  const int ER = in_sizes[3] / 18;
  const int R  = out_size;

  float* Wf = (float*)d_ws;
  size_t off = 0;
  // round allocations to even float counts so float2 views stay 8-B aligned
  auto alloc  = [&](size_t nf){ nf = (nf + 1) & ~(size_t)1; float* p = Wf + off; off += nf; return p; };
  auto alloci = [&](size_t ni){ ni = (ni + 1) & ~(size_t)1; int* p = (int*)(Wf + off); off += ni; return p; };

  // persistent head
  float* y0 = alloc((size_t)R * 400);
  float* y1 = alloc((size_t)R * 200);
  float* y2 = alloc((size_t)R * 100);
  float* y3 = alloc((size_t)R * 100);
  float* xp = alloc(128);
  float* v  = alloc(128);
  int* starts = alloci(R + 1);
  const size_t arena = off;

  // ================= rule path =================
  {
    off = arena;
    float* h1 = alloc((size_t)NR * 100);
    float* h2 = alloc((size_t)NR * 200);
    float* xl = alloc((size_t)NR * 200);
    float* xr = alloc((size_t)NR * 200);
    float2* lw = (float2*)alloc((size_t)ER * 2);
    int* rowoff = alloci(NR + 1);
    int* degi   = alloci(NR);
    int* pos    = alloci(NR);
    int* eidx   = alloci(ER);
    const int* rsrc = rei; const int* rdst = rei + ER;

    hipMemsetAsync(degi, 0, (size_t)NR * 4, stream);
    k_deg<<<nblk(ER), 256, 0, stream>>>(rdst, degi, ER);
    k_scan<<<1, 1024, 0, stream>>>(degi, rowoff, NR);
    hipMemcpyAsync(pos, rowoff, (size_t)NR * 4, hipMemcpyDeviceToDevice, stream);
    k_fill<<<nblk(ER), 256, 0, stream>>>(rdst, pos, eidx, ER);

    run_gatv2(rx, 16, 100, NR, rsrc, rdst, rea, ER, g1, h1, 1,
              xl, xr, lw, rowoff, eidx, stream);
    run_gatv2(h1, 100, 200, NR, rsrc, rdst, rea, ER, g2, h2, 1,
              xl, xr, lw, rowoff, eidx, stream);

    float* hlin = xl;  // NR*400 floats (xl+xr contiguous)
    gemm_launch(h2, lin_W, lin_b, hlin, NR, 200, 400, 0, stream);

    k_rule_starts<<<(R + 256) / 256, 256, 0, stream>>>(rb, starts, NR, R);
    k_pool_rules<<<nblk((long)R * 400), 256, 0, stream>>>(hlin, starts, y0, R, 400);

    gemm_launch(y0, f1_W, f1_b, y1, R, 400, 200, 1, stream);
    gemm_launch(y1, f2_W, f2_b, y2, R, 200, 100, 1, stream);
    gemm_launch(y2, f3_W, f3_b, y3, R, 100, 100, 0, stream);
  }

  // ================= data path =================
  {
    off = arena;
    float* g  = alloc((size_t)N * 100);
    float* xl = alloc((size_t)N * 100);
    float* xr = alloc((size_t)N * 100);
    float2* lw = (float2*)alloc((size_t)E * 2);
    int* rowoff = alloci((size_t)N + 1);
    int* degi   = alloci(N);
    int* pos    = alloci(N);
    int* eidx   = alloci(E);
    const int* srcp = ei; const int* dstp = ei + E;

    hipMemsetAsync(degi, 0, (size_t)N * 4, stream);
    k_deg<<<nblk(E), 256, 0, stream>>>(dstp, degi, E);
    k_scan<<<1, 1024, 0, stream>>>(degi, rowoff, N);
    hipMemcpyAsync(pos, rowoff, (size_t)N * 4, hipMemcpyDeviceToDevice, stream);
    k_fill<<<nblk(E), 256, 0, stream>>>(dstp, pos, eidx, E);

    run_gatv2(x, 16, 100, N, srcp, dstp, ea, E, g0, g, 0,
              xl, xr, lw, rowoff, eidx, stream);

    hipMemsetAsync(xp, 0, 128 * 4, stream);
    k_pool_all<<<nblk((long)N * 25), 256, 0, stream>>>(g, xp, (long)N * 25, 100);
    k_bil_v<<<1, 128, 0, stream>>>(xp, bilW, v, 1.0f / (float)N);
    k_bil_out<<<(R + 127) / 128, 128, 0, stream>>>(v, y3, bilb, (float*)d_out, R);
  }
}

// Round 7
// 1318.915 us; speedup vs baseline: 2.0223x; 1.0896x over previous
//
#include <hip/hip_runtime.h>

#define NS 0.2f  // leaky_relu negative slope

// ===================== CSR construction =====================
__global__ void k_deg(const int* __restrict__ dst, int* degi, int E){
  int stride = gridDim.x * blockDim.x;
  for(int e = blockIdx.x * blockDim.x + threadIdx.x; e < E; e += stride)
    atomicAdd(&degi[dst[e]], 1);
}

__device__ __forceinline__ int wave_iscan(int v, int lane){
  #pragma unroll
  for(int o = 1; o < 64; o <<= 1){
    int t = __shfl_up(v, o);
    if(lane >= o) v += t;
  }
  return v;
}

__global__ void k_scan(const int* __restrict__ deg, int* __restrict__ rowoff, int n){
  __shared__ int wsum[16];
  __shared__ int carry_s;
  const int lane = threadIdx.x & 63;
  const int w = threadIdx.x >> 6;
  if(threadIdx.x == 0) carry_s = 0;
  __syncthreads();
  for(int base = 0; base < n; base += 1024){
    int idx = base + (int)threadIdx.x;
    int v = (idx < n) ? deg[idx] : 0;
    int inc = wave_iscan(v, lane);
    if(lane == 63) wsum[w] = inc;
    __syncthreads();
    if(w == 0){
      int s = (lane < 16) ? wsum[lane] : 0;
      s = wave_iscan(s, lane);
      if(lane < 16) wsum[lane] = s;
    }
    __syncthreads();
    int woff = (w > 0) ? wsum[w - 1] : 0;
    int total = wsum[15];
    if(idx < n) rowoff[idx] = carry_s + woff + inc - v;
    __syncthreads();
    if(threadIdx.x == 0) carry_s += total;
    __syncthreads();
  }
  if(threadIdx.x == 0) rowoff[n] = carry_s;
}

__global__ void k_fill(const int* __restrict__ dst, int* pos, int* eidx, int E){
  int stride = gridDim.x * blockDim.x;
  for(int e = blockIdx.x * blockDim.x + threadIdx.x; e < E; e += stride){
    int slot = atomicAdd(&pos[dst[e]], 1);
    eidx[slot] = e;
  }
}

// ===================== ea_mean per node (lane-parallel, no dependent chain) =====================
// Lanes cover (edge-slot, feature) pairs: 3 groups of 18 lanes; group g handles
// CSR positions r0+g, r0+g+3, ... -> independent loads, 3x shorter chain.
__global__ __launch_bounds__(256) void k_easum(
    const float* __restrict__ ea, const int* __restrict__ rowoff,
    const int* __restrict__ eidx, float* __restrict__ eam, int n)
{
  const int lane = threadIdx.x & 63;
  const int wid  = threadIdx.x >> 6;
  const int i = blockIdx.x * 4 + wid;
  if(i >= n) return;
  const int r0 = rowoff[i], r1 = rowoff[i + 1];
  const int deg = r1 - r0;
  const int pg = lane / 18;          // 0..3 (group 3 idle)
  const int k  = lane - pg * 18;
  float s = 0.0f;
  if(pg < 3){
    for(int p = r0 + pg; p < r1; p += 3)
      s += ea[(long)eidx[p] * 18 + k];
  }
  float b = __shfl(s, lane + 18);
  float c = __shfl(s, lane + 36);
  if(lane < 18) eam[(long)i * 18 + lane] = (s + b + c) / fmaxf((float)deg, 1.0f);
}

// ===================== tiled GEMM: C = A @ W^T + b =====================
#define BM 64
#define BN 64
#define BK 16
__global__ __launch_bounds__(256) void k_gemm(
    const float* __restrict__ A, const float* __restrict__ W,
    const float* __restrict__ b, float* __restrict__ C,
    int n, int K, int M, int dorelu)
{
  __shared__ float As[BM][BK + 1];
  __shared__ float Bs[BN][BK + 1];
  const int bi = blockIdx.x * BM;
  const int bj = blockIdx.y * BN;
  const int tid = threadIdx.x;
  const int tr = tid / 16, tc = tid % 16;
  float acc[4][4] = {};
  for(int k0 = 0; k0 < K; k0 += BK){
    for(int l = tid; l < BM * BK; l += 256){
      int r = l / BK, c = l % BK;
      int gr = bi + r, gc = k0 + c;
      As[r][c] = (gr < n && gc < K) ? A[(long)gr * K + gc] : 0.0f;
    }
    for(int l = tid; l < BN * BK; l += 256){
      int r = l / BK, c = l % BK;
      int gr = bj + r, gc = k0 + c;
      Bs[r][c] = (gr < M && gc < K) ? W[(long)gr * K + gc] : 0.0f;
    }
    __syncthreads();
    #pragma unroll
    for(int kk = 0; kk < BK; ++kk){
      float av[4], bv[4];
      #pragma unroll
      for(int r = 0; r < 4; r++) av[r] = As[tr * 4 + r][kk];
      #pragma unroll
      for(int c = 0; c < 4; c++) bv[c] = Bs[tc * 4 + c][kk];
      #pragma unroll
      for(int r = 0; r < 4; r++)
        #pragma unroll
        for(int c = 0; c < 4; c++) acc[r][c] += av[r] * bv[c];
    }
    __syncthreads();
  }
  for(int r = 0; r < 4; r++){
    int gr = bi + tr * 4 + r;
    if(gr >= n) continue;
    for(int c = 0; c < 4; c++){
      int gc = bj + tc * 4 + c;
      if(gc >= M) continue;
      float val = acc[r][c] + b[gc];
      C[(long)gr * M + gc] = dorelu ? fmaxf(val, 0.0f) : val;
    }
  }
}

static void gemm_launch(const float* A, const float* W, const float* b, float* C,
                        int n, int K, int M, int relu, hipStream_t s){
  dim3 grid((n + BM - 1) / BM, (M + BN - 1) / BN);
  k_gemm<<<grid, 256, 0, s>>>(A, W, b, C, n, K, M, relu);
}

__device__ __forceinline__ float lkrelu(float t){ return (t > 0.0f) ? t : NS * t; }

// ===================== logits: G-lane group x NE=4 items, persistent blocks =====================
// SELF=false: items are CSR edge positions -> lw[p] = {logit, src}.
// SELF=true : items are nodes (src=dst=i, ea=eam)  -> slf[i] = logit.
template<int G, int F, bool SELF>
__global__ __launch_bounds__(256) void k_edge_logits(
    const float* __restrict__ xl, const float* __restrict__ xr,
    const float* __restrict__ ea,
    const int* __restrict__ src, const int* __restrict__ dst,
    const int* __restrict__ eidx,
    const float* __restrict__ We, const float* __restrict__ att,
    float2* __restrict__ lw, float* __restrict__ slf, int E)
{
  constexpr int NG = 256 / G;       // groups per block
  constexpr int NE = 4;             // items per group-iteration
  constexpr int FQ = F / 4;         // float4s per feature row
  __shared__ float4 sWeT[18 * FQ];  // [k][f4], transposed
  __shared__ float4 sAtt[FQ];
  __shared__ float4 sEa[NG][18];    // [k] -> (ea_e0, ea_e1, ea_e2, ea_e3)
  __shared__ int    sIdx[NG][3][NE];// [0]=e, [1]=src, [2]=dst

  const int tid = threadIdx.x;
  for(int idx = tid; idx < F * 18; idx += 256){
    int f = idx / 18, k = idx % 18;            // coalesced global read
    ((float*)sWeT)[k * F + f] = We[idx];
  }
  for(int f = tid; f < F; f += 256) ((float*)sAtt)[f] = att[f];
  __syncthreads();

  const int g  = tid / G;
  const int gl = tid % G;
  const bool act = (gl * 4 < F);
  const int glc = act ? gl : 0;
  const long step = (long)gridDim.x * (NG * NE);

  for(long base = (long)blockIdx.x * (NG * NE); base < (long)E; base += step){
    const long pb = base + (long)g * NE;
    // --- stage item ids for this group's 4 positions ---
    if(gl < NE){
      long p = pb + gl;
      int e = -1, s = 0, d = 0;
      if(p < (long)E){
        if(SELF){ e = (int)p; s = e; d = e; }
        else    { e = eidx[p]; s = src[e]; d = dst[e]; }
      }
      sIdx[g][0][gl] = e; sIdx[g][1][gl] = s; sIdx[g][2][gl] = d;
    }
    // --- stage 4 ea rows, packed k-major with ne in float4 lanes ---
    #pragma unroll
    for(int t = 0; t < (18 * NE + G - 1) / G; ++t){
      int u = t * G + gl;
      if(u < 18 * NE){
        int ne = u & 3, k = u >> 2;
        int e = sIdx[g][0][ne];
        ((float*)&sEa[g][k])[ne] = (e >= 0) ? ea[(long)e * 18 + k] : 0.0f;
      }
    }
    int4 sv = *(const int4*)&sIdx[g][1][0];
    int4 dv = *(const int4*)&sIdx[g][2][0];
    // --- gather full xl/xr rows (contiguous float4 per lane) ---
    float4 a0 = *(const float4*)(xl + (long)sv.x * F + glc * 4);
    float4 b0 = *(const float4*)(xr + (long)dv.x * F + glc * 4);
    float4 a1 = *(const float4*)(xl + (long)sv.y * F + glc * 4);
    float4 b1 = *(const float4*)(xr + (long)dv.y * F + glc * 4);
    float4 a2 = *(const float4*)(xl + (long)sv.z * F + glc * 4);
    float4 b2 = *(const float4*)(xr + (long)dv.z * F + glc * 4);
    float4 a3 = *(const float4*)(xl + (long)sv.w * F + glc * 4);
    float4 b3 = *(const float4*)(xr + (long)dv.w * F + glc * 4);
    float4 t0 = make_float4(a0.x + b0.x, a0.y + b0.y, a0.z + b0.z, a0.w + b0.w);
    float4 t1 = make_float4(a1.x + b1.x, a1.y + b1.y, a1.z + b1.z, a1.w + b1.w);
    float4 t2 = make_float4(a2.x + b2.x, a2.y + b2.y, a2.z + b2.z, a2.w + b2.w);
    float4 t3 = make_float4(a3.x + b3.x, a3.y + b3.y, a3.z + b3.z, a3.w + b3.w);
    // --- We @ ea for 4 items: 2 LDS reads + 16 FMA per k ---
    #pragma unroll
    for(int k = 0; k < 18; ++k){
      float4 w  = sWeT[k * FQ + glc];
      float4 eq = sEa[g][k];
      t0.x = fmaf(w.x, eq.x, t0.x); t0.y = fmaf(w.y, eq.x, t0.y);
      t0.z = fmaf(w.z, eq.x, t0.z); t0.w = fmaf(w.w, eq.x, t0.w);
      t1.x = fmaf(w.x, eq.y, t1.x); t1.y = fmaf(w.y, eq.y, t1.y);
      t1.z = fmaf(w.z, eq.y, t1.z); t1.w = fmaf(w.w, eq.y, t1.w);
      t2.x = fmaf(w.x, eq.z, t2.x); t2.y = fmaf(w.y, eq.z, t2.y);
      t2.z = fmaf(w.z, eq.z, t2.z); t2.w = fmaf(w.w, eq.z, t2.w);
      t3.x = fmaf(w.x, eq.w, t3.x); t3.y = fmaf(w.y, eq.w, t3.y);
      t3.z = fmaf(w.z, eq.w, t3.z); t3.w = fmaf(w.w, eq.w, t3.w);
    }
    // --- leaky + att dot ---
    float4 av = sAtt[glc];
    float r0 = 0, r1 = 0, r2 = 0, r3 = 0;
    if(act){
      r0 = av.x * lkrelu(t0.x) + av.y * lkrelu(t0.y) + av.z * lkrelu(t0.z) + av.w * lkrelu(t0.w);
      r1 = av.x * lkrelu(t1.x) + av.y * lkrelu(t1.y) + av.z * lkrelu(t1.z) + av.w * lkrelu(t1.w);
      r2 = av.x * lkrelu(t2.x) + av.y * lkrelu(t2.y) + av.z * lkrelu(t2.z) + av.w * lkrelu(t2.w);
      r3 = av.x * lkrelu(t3.x) + av.y * lkrelu(t3.y) + av.z * lkrelu(t3.z) + av.w * lkrelu(t3.w);
    }
    #pragma unroll
    for(int o = G / 2; o; o >>= 1){
      r0 += __shfl_xor(r0, o);
      r1 += __shfl_xor(r1, o);
      r2 += __shfl_xor(r2, o);
      r3 += __shfl_xor(r3, o);
    }
    if(SELF){
      if(gl == 0 && pb + 0 < (long)E) slf[pb + 0] = r0;
      if(gl == 1 && pb + 1 < (long)E) slf[pb + 1] = r1;
      if(gl == 2 && pb + 2 < (long)E) slf[pb + 2] = r2;
      if(gl == 3 && pb + 3 < (long)E) slf[pb + 3] = r3;
    } else {
      if(gl == 0 && pb + 0 < (long)E) lw[pb + 0] = make_float2(r0, __int_as_float(sv.x));
      if(gl == 1 && pb + 1 < (long)E) lw[pb + 1] = make_float2(r1, __int_as_float(sv.y));
      if(gl == 2 && pb + 2 < (long)E) lw[pb + 2] = make_float2(r2, __int_as_float(sv.z));
      if(gl == 3 && pb + 3 < (long)E) lw[pb + 3] = make_float2(r3, __int_as_float(sv.w));
    }
  }
}

// ===================== node softmax + aggregate: one WAVE per node =====================
// Self/ea work hoisted out; gather loop unrolled x4 for memory-level parallelism.
#define CH 128
template<int JMAX>
__global__ __launch_bounds__(256) void k_gat_agg(
    const float* __restrict__ xl,
    const int* __restrict__ rowoff,
    const float2* __restrict__ lw, const float* __restrict__ selfl,
    const float* __restrict__ bias, float* __restrict__ out,
    int n, int F, int dorelu)
{
  const int lane = threadIdx.x & 63;
  const int wid  = threadIdx.x >> 6;
  __shared__ float2 s_ws[4][CH];   // {weight, src bits}
  const int i = blockIdx.x * 4 + wid;
  if(i >= n) return;          // wave-uniform exit; no __syncthreads below
  const int r0 = rowoff[i], r1 = rowoff[i + 1];
  const int deg = r1 - r0;

  // ---- init online softmax from precomputed self logit (weight 1 at m) ----
  float m = selfl[i], denom = 1.0f;
  float acc[JMAX];
  #pragma unroll
  for(int j = 0; j < JMAX; ++j){
    int f = lane + j * 64;
    acc[j] = (f < F) ? xl[(long)i * F + f] : 0.0f;
  }

  // ---- chunks of incident edges ----
  for(int c0 = 0; c0 < deg; c0 += CH){
    int cn = min(CH, deg - c0);
    // coalesced stream of {logit, src} in CSR order
    float lmax = -3.4e38f;
    for(int q = lane; q < cn; q += 64){
      float2 ws = lw[r0 + c0 + q];
      s_ws[wid][q] = ws;
      lmax = fmaxf(lmax, ws.x);
    }
    #pragma unroll
    for(int o = 32; o; o >>= 1) lmax = fmaxf(lmax, __shfl_xor(lmax, o));
    float newm = fmaxf(m, lmax);
    float scale = expf(m - newm);
    denom *= scale;
    #pragma unroll
    for(int j = 0; j < JMAX; ++j) acc[j] *= scale;
    m = newm;
    float psum = 0.0f;
    for(int q = lane; q < cn; q += 64){
      float2 ws = s_ws[wid][q];
      float w = expf(ws.x - m);
      s_ws[wid][q].x = w;
      psum += w;
    }
    #pragma unroll
    for(int o = 32; o; o >>= 1) psum += __shfl_xor(psum, o);
    denom += psum;
    // gather-aggregate, 4 edges in flight
    int p = 0;
    for(; p + 4 <= cn; p += 4){
      float2 w0 = s_ws[wid][p + 0];
      float2 w1 = s_ws[wid][p + 1];
      float2 w2 = s_ws[wid][p + 2];
      float2 w3 = s_ws[wid][p + 3];
      const float* x0 = xl + (long)__float_as_int(w0.y) * F;
      const float* x1 = xl + (long)__float_as_int(w1.y) * F;
      const float* x2 = xl + (long)__float_as_int(w2.y) * F;
      const float* x3 = xl + (long)__float_as_int(w3.y) * F;
      float v0[JMAX], v1[JMAX], v2[JMAX], v3[JMAX];
      #pragma unroll
      for(int j = 0; j < JMAX; ++j){
        int f = lane + j * 64; bool okf = f < F;
        v0[j] = okf ? x0[f] : 0.0f;
        v1[j] = okf ? x1[f] : 0.0f;
        v2[j] = okf ? x2[f] : 0.0f;
        v3[j] = okf ? x3[f] : 0.0f;
      }
      #pragma unroll
      for(int j = 0; j < JMAX; ++j){
        acc[j] = fmaf(w0.x, v0[j], acc[j]);
        acc[j] = fmaf(w1.x, v1[j], acc[j]);
        acc[j] = fmaf(w2.x, v2[j], acc[j]);
        acc[j] = fmaf(w3.x, v3[j], acc[j]);
      }
    }
    for(; p < cn; ++p){
      float2 ws = s_ws[wid][p];
      const float* xs = xl + (long)__float_as_int(ws.y) * F;
      #pragma unroll
      for(int j = 0; j < JMAX; ++j){
        int f = lane + j * 64;
        if(f < F) acc[j] = fmaf(ws.x, xs[f], acc[j]);
      }
    }
  }

  // ---- write ----
  float inv = 1.0f / denom;
  #pragma unroll
  for(int j = 0; j < JMAX; ++j){
    int f = lane + j * 64;
    if(f < F){
      float o = acc[j] * inv + bias[f];
      out[(long)i * F + f] = dorelu ? fmaxf(o, 0.0f) : o;
    }
  }
}

// ===================== rule pooling (rule_batch sorted) =====================
__global__ void k_rule_starts(const int* __restrict__ rb, int* starts, int NR, int R){
  int r = blockIdx.x * blockDim.x + threadIdx.x;
  if(r > R) return;
  if(r == R){ starts[R] = NR; return; }
  int lo = 0, hi = NR;
  while(lo < hi){ int mid = (lo + hi) >> 1; if(rb[mid] < r) lo = mid + 1; else hi = mid; }
  starts[r] = lo;
}

__global__ void k_pool_rules(const float* __restrict__ h, const int* __restrict__ starts,
                             float* __restrict__ y, int R, int F){
  long idx = (long)blockIdx.x * blockDim.x + threadIdx.x;
  long total = (long)R * F;
  if(idx >= total) return;
  int r = (int)(idx / F);
  int f = (int)(idx % F);
  int s0 = starts[r], s1 = starts[r + 1];
  float a = 0.0f;
  for(int i = s0; i < s1; i++) a += h[(long)i * F + f];
  y[idx] = a / fmaxf((float)(s1 - s0), 1.0f);
}

// ===================== global mean + bilinear =====================
__global__ void k_pool_all(const float* __restrict__ g, float* xp, long total4, int F){
  __shared__ float s[128];
  for(int j = threadIdx.x; j < F; j += blockDim.x) s[j] = 0.0f;
  __syncthreads();
  long stride = (long)gridDim.x * blockDim.x;
  const float4* g4 = (const float4*)g;
  for(long idx = (long)blockIdx.x * blockDim.x + threadIdx.x; idx < total4; idx += stride){
    float4 v = g4[idx];
    long base = idx * 4;
    atomicAdd(&s[(int)((base + 0) % F)], v.x);
    atomicAdd(&s[(int)((base + 1) % F)], v.y);
    atomicAdd(&s[(int)((base + 2) % F)], v.z);
    atomicAdd(&s[(int)((base + 3) % F)], v.w);
  }
  __syncthreads();
  for(int j = threadIdx.x; j < F; j += blockDim.x){
    float v = s[j];
    if(v != 0.0f) atomicAdd(&xp[j], v);
  }
}

__global__ void k_bil_v(const float* __restrict__ xp, const float* __restrict__ Wb,
                        float* v, float inv_n){
  int e = threadIdx.x;
  if(e < 100){
    float a = 0.0f;
    for(int d = 0; d < 100; d++) a += xp[d] * Wb[d * 100 + e];
    v[e] = a * inv_n;
  }
}

__global__ void k_bil_out(const float* __restrict__ v, const float* __restrict__ y,
                          const float* __restrict__ bilb, float* out, int R){
  int r = blockIdx.x * blockDim.x + threadIdx.x;
  if(r < R){
    float a = 0.0f;
    const float* yr = y + (long)r * 100;
    for(int e = 0; e < 100; e++) a += v[e] * yr[e];
    out[r] = a + bilb[0];
  }
}

// ------------------------------------------------------------------
static inline int nblk(long n){
  long b = (n + 255) / 256;
  if(b > 20480) b = 20480;
  if(b < 1) b = 1;
  return (int)b;
}

struct GatParams { const float *Wl,*bl,*Wr,*br,*We,*att,*b; };

template<int G, int F, bool SELF>
static void logits_launch(const float* xl, const float* xr, const float* ea,
                          const int* src, const int* dst, const int* eidx,
                          const float* We, const float* att, float2* lw, float* slf,
                          int E, hipStream_t stream){
  const int epb = (256 / G) * 4;   // items per block-iteration
  long nb = ((long)E + epb - 1) / epb;
  int grid = (int)(nb < 2048 ? nb : 2048);
  k_edge_logits<G, F, SELF><<<grid, 256, 0, stream>>>(xl, xr, ea, src, dst, eidx,
                                                      We, att, lw, slf, E);
}

static void run_gatv2(const float* x, int fin, int fout, int n,
                      const int* src, const int* dst, const float* ea, int E,
                      GatParams P, float* out, int dorelu,
                      float* xl, float* xr, float2* lw, float* selfl,
                      const float* eam, const int* rowoff, const int* eidx,
                      hipStream_t stream){
  gemm_launch(x, P.Wl, P.bl, xl, n, fin, fout, 0, stream);
  gemm_launch(x, P.Wr, P.br, xr, n, fin, fout, 0, stream);
  if(fout == 100){
    logits_launch<32, 100, false>(xl, xr, ea, src, dst, eidx, P.We, P.att, lw, nullptr, E, stream);
    logits_launch<32, 100, true >(xl, xr, eam, nullptr, nullptr, nullptr, P.We, P.att, nullptr, selfl, n, stream);
    k_gat_agg<2><<<(n + 3) / 4, 256, 0, stream>>>(xl, rowoff, lw, selfl, P.b, out, n, fout, dorelu);
  } else {
    logits_launch<64, 200, false>(xl, xr, ea, src, dst, eidx, P.We, P.att, lw, nullptr, E, stream);
    logits_launch<64, 200, true >(xl, xr, eam, nullptr, nullptr, nullptr, P.We, P.att, nullptr, selfl, n, stream);
    k_gat_agg<4><<<(n + 3) / 4, 256, 0, stream>>>(xl, rowoff, lw, selfl, P.b, out, n, fout, dorelu);
  }
}

extern "C" void kernel_launch(void* const* d_in, const int* in_sizes, int n_in,
                              void* d_out, int out_size, void* d_ws, size_t ws_size,
                              hipStream_t stream){
  const float* x   = (const float*)d_in[0];
  const float* ea  = (const float*)d_in[1];
  const float* rx  = (const float*)d_in[2];
  const float* rea = (const float*)d_in[3];
  GatParams g0{ (const float*)d_in[4],  (const float*)d_in[5],  (const float*)d_in[6],
                (const float*)d_in[7],  (const float*)d_in[8],  (const float*)d_in[9],
                (const float*)d_in[10] };
  GatParams g1{ (const float*)d_in[11], (const float*)d_in[12], (const float*)d_in[13],
                (const float*)d_in[14], (const float*)d_in[15], (const float*)d_in[16],
                (const float*)d_in[17] };
  GatParams g2{ (const float*)d_in[18], (const float*)d_in[19], (const float*)d_in[20],
                (const float*)d_in[21], (const float*)d_in[22], (const float*)d_in[23],
                (const float*)d_in[24] };
  const float* lin_W = (const float*)d_in[25]; const float* lin_b = (const float*)d_in[26];
  const float* f1_W  = (const float*)d_in[27]; const float* f1_b  = (const float*)d_in[28];
  const float* f2_W  = (const float*)d_in[29]; const float* f2_b  = (const float*)d_in[30];
  const float* f3_W  = (const float*)d_in[31]; const float* f3_b  = (const float*)d_in[32];
  const float* bilW  = (const float*)d_in[33]; const float* bilb  = (const float*)d_in[34];
  const int* ei  = (const int*)d_in[35];
  const int* rei = (const int*)d_in[37];
  const int* rb  = (const int*)d_in[38];

  const int N  = in_sizes[0] / 16;
  const int E  = in_sizes[1] / 18;
  const int NR = in_sizes[2] / 16;
  const int ER = in_sizes[3] / 18;
  const int R  = out_size;

  float* Wf = (float*)d_ws;
  size_t off = 0;
  // round allocations to even float counts so float2 views stay 8-B aligned
  auto alloc  = [&](size_t nf){ nf = (nf + 1) & ~(size_t)1; float* p = Wf + off; off += nf; return p; };
  auto alloci = [&](size_t ni){ ni = (ni + 1) & ~(size_t)1; int* p = (int*)(Wf + off); off += ni; return p; };

  // persistent head
  float* y0 = alloc((size_t)R * 400);
  float* y1 = alloc((size_t)R * 200);
  float* y2 = alloc((size_t)R * 100);
  float* y3 = alloc((size_t)R * 100);
  float* xp = alloc(128);
  float* v  = alloc(128);
  int* starts = alloci(R + 1);
  const size_t arena = off;

  // ================= rule path =================
  {
    off = arena;
    float* h1 = alloc((size_t)NR * 100);
    float* h2 = alloc((size_t)NR * 200);
    float* xl = alloc((size_t)NR * 200);
    float* xr = alloc((size_t)NR * 200);
    float2* lw = (float2*)alloc((size_t)ER * 2);
    float* eam   = alloc((size_t)NR * 18);
    float* selfl = alloc(NR);
    int* rowoff = alloci(NR + 1);
    int* degi   = alloci(NR);
    int* pos    = alloci(NR);
    int* eidx   = alloci(ER);
    const int* rsrc = rei; const int* rdst = rei + ER;

    hipMemsetAsync(degi, 0, (size_t)NR * 4, stream);
    k_deg<<<nblk(ER), 256, 0, stream>>>(rdst, degi, ER);
    k_scan<<<1, 1024, 0, stream>>>(degi, rowoff, NR);
    hipMemcpyAsync(pos, rowoff, (size_t)NR * 4, hipMemcpyDeviceToDevice, stream);
    k_fill<<<nblk(ER), 256, 0, stream>>>(rdst, pos, eidx, ER);
    k_easum<<<(NR + 3) / 4, 256, 0, stream>>>(rea, rowoff, eidx, eam, NR);

    run_gatv2(rx, 16, 100, NR, rsrc, rdst, rea, ER, g1, h1, 1,
              xl, xr, lw, selfl, eam, rowoff, eidx, stream);
    run_gatv2(h1, 100, 200, NR, rsrc, rdst, rea, ER, g2, h2, 1,
              xl, xr, lw, selfl, eam, rowoff, eidx, stream);

    float* hlin = xl;  // NR*400 floats (xl+xr contiguous)
    gemm_launch(h2, lin_W, lin_b, hlin, NR, 200, 400, 0, stream);

    k_rule_starts<<<(R + 256) / 256, 256, 0, stream>>>(rb, starts, NR, R);
    k_pool_rules<<<nblk((long)R * 400), 256, 0, stream>>>(hlin, starts, y0, R, 400);

    gemm_launch(y0, f1_W, f1_b, y1, R, 400, 200, 1, stream);
    gemm_launch(y1, f2_W, f2_b, y2, R, 200, 100, 1, stream);
    gemm_launch(y2, f3_W, f3_b, y3, R, 100, 100, 0, stream);
  }

  // ================= data path =================
  {
    off = arena;
    float* g  = alloc((size_t)N * 100);
    float* xl = alloc((size_t)N * 100);
    float* xr = alloc((size_t)N * 100);
    float2* lw = (float2*)alloc((size_t)E * 2);
    float* eam   = alloc((size_t)N * 18);
    float* selfl = alloc(N);
    int* rowoff = alloci((size_t)N + 1);
    int* degi   = alloci(N);
    int* pos    = alloci(N);
    int* eidx   = alloci(E);
    const int* srcp = ei; const int* dstp = ei + E;

    hipMemsetAsync(degi, 0, (size_t)N * 4, stream);
    k_deg<<<nblk(E), 256, 0, stream>>>(dstp, degi, E);
    k_scan<<<1, 1024, 0, stream>>>(degi, rowoff, N);
    hipMemcpyAsync(pos, rowoff, (size_t)N * 4, hipMemcpyDeviceToDevice, stream);
    k_fill<<<nblk(E), 256, 0, stream>>>(dstp, pos, eidx, E);
    k_easum<<<(N + 3) / 4, 256, 0, stream>>>(ea, rowoff, eidx, eam, N);

    run_gatv2(x, 16, 100, N, srcp, dstp, ea, E, g0, g, 0,
              xl, xr, lw, selfl, eam, rowoff, eidx, stream);

    hipMemsetAsync(xp, 0, 128 * 4, stream);
    k_pool_all<<<nblk((long)N * 25), 256, 0, stream>>>(g, xp, (long)N * 25, 100);
    k_bil_v<<<1, 128, 0, stream>>>(xp, bilW, v, 1.0f / (float)N);
    k_bil_out<<<(R + 127) / 128, 128, 0, stream>>>(v, y3, bilb, (float*)d_out, R);
  }
}

// Round 8
// 1183.666 us; speedup vs baseline: 2.2534x; 1.1143x over previous
//
#include <hip/hip_runtime.h>

#define NS 0.2f  // leaky_relu negative slope

// ===================== CSR construction =====================
__global__ void k_deg(const int* __restrict__ dst, int* degi, int E){
  int stride = gridDim.x * blockDim.x;
  for(int e = blockIdx.x * blockDim.x + threadIdx.x; e < E; e += stride)
    atomicAdd(&degi[dst[e]], 1);
}

__device__ __forceinline__ int wave_iscan(int v, int lane){
  #pragma unroll
  for(int o = 1; o < 64; o <<= 1){
    int t = __shfl_up(v, o);
    if(lane >= o) v += t;
  }
  return v;
}

__global__ void k_scan(const int* __restrict__ deg, int* __restrict__ rowoff, int n){
  __shared__ int wsum[16];
  __shared__ int carry_s;
  const int lane = threadIdx.x & 63;
  const int w = threadIdx.x >> 6;
  if(threadIdx.x == 0) carry_s = 0;
  __syncthreads();
  for(int base = 0; base < n; base += 1024){
    int idx = base + (int)threadIdx.x;
    int v = (idx < n) ? deg[idx] : 0;
    int inc = wave_iscan(v, lane);
    if(lane == 63) wsum[w] = inc;
    __syncthreads();
    if(w == 0){
      int s = (lane < 16) ? wsum[lane] : 0;
      s = wave_iscan(s, lane);
      if(lane < 16) wsum[lane] = s;
    }
    __syncthreads();
    int woff = (w > 0) ? wsum[w - 1] : 0;
    int total = wsum[15];
    if(idx < n) rowoff[idx] = carry_s + woff + inc - v;
    __syncthreads();
    if(threadIdx.x == 0) carry_s += total;
    __syncthreads();
  }
  if(threadIdx.x == 0) rowoff[n] = carry_s;
}

__global__ void k_fill(const int* __restrict__ dst, int* pos, int* eidx, int E){
  int stride = gridDim.x * blockDim.x;
  for(int e = blockIdx.x * blockDim.x + threadIdx.x; e < E; e += stride){
    int slot = atomicAdd(&pos[dst[e]], 1);
    eidx[slot] = e;
  }
}

// ===================== ea_mean per node (lane-parallel, no dependent chain) =====================
__global__ __launch_bounds__(256) void k_easum(
    const float* __restrict__ ea, const int* __restrict__ rowoff,
    const int* __restrict__ eidx, float* __restrict__ eam, int n)
{
  const int lane = threadIdx.x & 63;
  const int wid  = threadIdx.x >> 6;
  const int i = blockIdx.x * 4 + wid;
  if(i >= n) return;
  const int r0 = rowoff[i], r1 = rowoff[i + 1];
  const int deg = r1 - r0;
  const int pg = lane / 18;          // 0..3 (group 3 idle)
  const int k  = lane - pg * 18;
  float s = 0.0f;
  if(pg < 3){
    for(int p = r0 + pg; p < r1; p += 3)
      s += ea[(long)eidx[p] * 18 + k];
  }
  float b = __shfl(s, lane + 18);
  float c = __shfl(s, lane + 36);
  if(lane < 18) eam[(long)i * 18 + lane] = (s + b + c) / fmaxf((float)deg, 1.0f);
}

// ===================== tiled GEMM: C = A @ W^T + b =====================
#define BM 64
#define BN 64
#define BK 16
__global__ __launch_bounds__(256) void k_gemm(
    const float* __restrict__ A, const float* __restrict__ W,
    const float* __restrict__ b, float* __restrict__ C,
    int n, int K, int M, int dorelu)
{
  __shared__ float As[BM][BK + 1];
  __shared__ float Bs[BN][BK + 1];
  const int bi = blockIdx.x * BM;
  const int bj = blockIdx.y * BN;
  const int tid = threadIdx.x;
  const int tr = tid / 16, tc = tid % 16;
  float acc[4][4] = {};
  for(int k0 = 0; k0 < K; k0 += BK){
    for(int l = tid; l < BM * BK; l += 256){
      int r = l / BK, c = l % BK;
      int gr = bi + r, gc = k0 + c;
      As[r][c] = (gr < n && gc < K) ? A[(long)gr * K + gc] : 0.0f;
    }
    for(int l = tid; l < BN * BK; l += 256){
      int r = l / BK, c = l % BK;
      int gr = bj + r, gc = k0 + c;
      Bs[r][c] = (gr < M && gc < K) ? W[(long)gr * K + gc] : 0.0f;
    }
    __syncthreads();
    #pragma unroll
    for(int kk = 0; kk < BK; ++kk){
      float av[4], bv[4];
      #pragma unroll
      for(int r = 0; r < 4; r++) av[r] = As[tr * 4 + r][kk];
      #pragma unroll
      for(int c = 0; c < 4; c++) bv[c] = Bs[tc * 4 + c][kk];
      #pragma unroll
      for(int r = 0; r < 4; r++)
        #pragma unroll
        for(int c = 0; c < 4; c++) acc[r][c] += av[r] * bv[c];
    }
    __syncthreads();
  }
  for(int r = 0; r < 4; r++){
    int gr = bi + tr * 4 + r;
    if(gr >= n) continue;
    for(int c = 0; c < 4; c++){
      int gc = bj + tc * 4 + c;
      if(gc >= M) continue;
      float val = acc[r][c] + b[gc];
      C[(long)gr * M + gc] = dorelu ? fmaxf(val, 0.0f) : val;
    }
  }
}

static void gemm_launch(const float* A, const float* W, const float* b, float* C,
                        int n, int K, int M, int relu, hipStream_t s){
  dim3 grid((n + BM - 1) / BM, (M + BN - 1) / BN);
  k_gemm<<<grid, 256, 0, s>>>(A, W, b, C, n, K, M, relu);
}

__device__ __forceinline__ float lkrelu(float t){ return (t > 0.0f) ? t : NS * t; }

// ===================== logits: G-lane group x NE=4 items, persistent blocks =====================
template<int G, int F, bool SELF>
__global__ __launch_bounds__(256) void k_edge_logits(
    const float* __restrict__ xl, const float* __restrict__ xr,
    const float* __restrict__ ea,
    const int* __restrict__ src, const int* __restrict__ dst,
    const int* __restrict__ eidx,
    const float* __restrict__ We, const float* __restrict__ att,
    float2* __restrict__ lw, float* __restrict__ slf, int E)
{
  constexpr int NG = 256 / G;       // groups per block
  constexpr int NE = 4;             // items per group-iteration
  constexpr int FQ = F / 4;         // float4s per feature row
  __shared__ float4 sWeT[18 * FQ];  // [k][f4], transposed
  __shared__ float4 sAtt[FQ];
  __shared__ float4 sEa[NG][18];    // [k] -> (ea_e0, ea_e1, ea_e2, ea_e3)
  __shared__ int    sIdx[NG][3][NE];// [0]=e, [1]=src, [2]=dst

  const int tid = threadIdx.x;
  for(int idx = tid; idx < F * 18; idx += 256){
    int f = idx / 18, k = idx % 18;            // coalesced global read
    ((float*)sWeT)[k * F + f] = We[idx];
  }
  for(int f = tid; f < F; f += 256) ((float*)sAtt)[f] = att[f];
  __syncthreads();

  const int g  = tid / G;
  const int gl = tid % G;
  const bool act = (gl * 4 < F);
  const int glc = act ? gl : 0;
  const long step = (long)gridDim.x * (NG * NE);

  for(long base = (long)blockIdx.x * (NG * NE); base < (long)E; base += step){
    const long pb = base + (long)g * NE;
    if(gl < NE){
      long p = pb + gl;
      int e = -1, s = 0, d = 0;
      if(p < (long)E){
        if(SELF){ e = (int)p; s = e; d = e; }
        else    { e = eidx[p]; s = src[e]; d = dst[e]; }
      }
      sIdx[g][0][gl] = e; sIdx[g][1][gl] = s; sIdx[g][2][gl] = d;
    }
    #pragma unroll
    for(int t = 0; t < (18 * NE + G - 1) / G; ++t){
      int u = t * G + gl;
      if(u < 18 * NE){
        int ne = u & 3, k = u >> 2;
        int e = sIdx[g][0][ne];
        ((float*)&sEa[g][k])[ne] = (e >= 0) ? ea[(long)e * 18 + k] : 0.0f;
      }
    }
    int4 sv = *(const int4*)&sIdx[g][1][0];
    int4 dv = *(const int4*)&sIdx[g][2][0];
    float4 a0 = *(const float4*)(xl + (long)sv.x * F + glc * 4);
    float4 b0 = *(const float4*)(xr + (long)dv.x * F + glc * 4);
    float4 a1 = *(const float4*)(xl + (long)sv.y * F + glc * 4);
    float4 b1 = *(const float4*)(xr + (long)dv.y * F + glc * 4);
    float4 a2 = *(const float4*)(xl + (long)sv.z * F + glc * 4);
    float4 b2 = *(const float4*)(xr + (long)dv.z * F + glc * 4);
    float4 a3 = *(const float4*)(xl + (long)sv.w * F + glc * 4);
    float4 b3 = *(const float4*)(xr + (long)dv.w * F + glc * 4);
    float4 t0 = make_float4(a0.x + b0.x, a0.y + b0.y, a0.z + b0.z, a0.w + b0.w);
    float4 t1 = make_float4(a1.x + b1.x, a1.y + b1.y, a1.z + b1.z, a1.w + b1.w);
    float4 t2 = make_float4(a2.x + b2.x, a2.y + b2.y, a2.z + b2.z, a2.w + b2.w);
    float4 t3 = make_float4(a3.x + b3.x, a3.y + b3.y, a3.z + b3.z, a3.w + b3.w);
    #pragma unroll
    for(int k = 0; k < 18; ++k){
      float4 w  = sWeT[k * FQ + glc];
      float4 eq = sEa[g][k];
      t0.x = fmaf(w.x, eq.x, t0.x); t0.y = fmaf(w.y, eq.x, t0.y);
      t0.z = fmaf(w.z, eq.x, t0.z); t0.w = fmaf(w.w, eq.x, t0.w);
      t1.x = fmaf(w.x, eq.y, t1.x); t1.y = fmaf(w.y, eq.y, t1.y);
      t1.z = fmaf(w.z, eq.y, t1.z); t1.w = fmaf(w.w, eq.y, t1.w);
      t2.x = fmaf(w.x, eq.z, t2.x); t2.y = fmaf(w.y, eq.z, t2.y);
      t2.z = fmaf(w.z, eq.z, t2.z); t2.w = fmaf(w.w, eq.z, t2.w);
      t3.x = fmaf(w.x, eq.w, t3.x); t3.y = fmaf(w.y, eq.w, t3.y);
      t3.z = fmaf(w.z, eq.w, t3.z); t3.w = fmaf(w.w, eq.w, t3.w);
    }
    float4 av = sAtt[glc];
    float r0 = 0, r1 = 0, r2 = 0, r3 = 0;
    if(act){
      r0 = av.x * lkrelu(t0.x) + av.y * lkrelu(t0.y) + av.z * lkrelu(t0.z) + av.w * lkrelu(t0.w);
      r1 = av.x * lkrelu(t1.x) + av.y * lkrelu(t1.y) + av.z * lkrelu(t1.z) + av.w * lkrelu(t1.w);
      r2 = av.x * lkrelu(t2.x) + av.y * lkrelu(t2.y) + av.z * lkrelu(t2.z) + av.w * lkrelu(t2.w);
      r3 = av.x * lkrelu(t3.x) + av.y * lkrelu(t3.y) + av.z * lkrelu(t3.z) + av.w * lkrelu(t3.w);
    }
    #pragma unroll
    for(int o = G / 2; o; o >>= 1){
      r0 += __shfl_xor(r0, o);
      r1 += __shfl_xor(r1, o);
      r2 += __shfl_xor(r2, o);
      r3 += __shfl_xor(r3, o);
    }
    if(SELF){
      if(gl == 0 && pb + 0 < (long)E) slf[pb + 0] = r0;
      if(gl == 1 && pb + 1 < (long)E) slf[pb + 1] = r1;
      if(gl == 2 && pb + 2 < (long)E) slf[pb + 2] = r2;
      if(gl == 3 && pb + 3 < (long)E) slf[pb + 3] = r3;
    } else {
      if(gl == 0 && pb + 0 < (long)E) lw[pb + 0] = make_float2(r0, __int_as_float(sv.x));
      if(gl == 1 && pb + 1 < (long)E) lw[pb + 1] = make_float2(r1, __int_as_float(sv.y));
      if(gl == 2 && pb + 2 < (long)E) lw[pb + 2] = make_float2(r2, __int_as_float(sv.z));
      if(gl == 3 && pb + 3 < (long)E) lw[pb + 3] = make_float2(r3, __int_as_float(sv.w));
    }
  }
}

// ===================== node softmax + aggregate: one WAVE per node =====================
#define CH 128
template<int JMAX>
__global__ __launch_bounds__(256) void k_gat_agg(
    const float* __restrict__ xl,
    const int* __restrict__ rowoff,
    const float2* __restrict__ lw, const float* __restrict__ selfl,
    const float* __restrict__ bias, float* __restrict__ out,
    int n, int F, int dorelu)
{
  const int lane = threadIdx.x & 63;
  const int wid  = threadIdx.x >> 6;
  __shared__ float2 s_ws[4][CH];   // {weight, src bits}
  const int i = blockIdx.x * 4 + wid;
  if(i >= n) return;          // wave-uniform exit; no __syncthreads below
  const int r0 = rowoff[i], r1 = rowoff[i + 1];
  const int deg = r1 - r0;

  float m = selfl[i], denom = 1.0f;
  float acc[JMAX];
  #pragma unroll
  for(int j = 0; j < JMAX; ++j){
    int f = lane + j * 64;
    acc[j] = (f < F) ? xl[(long)i * F + f] : 0.0f;
  }

  for(int c0 = 0; c0 < deg; c0 += CH){
    int cn = min(CH, deg - c0);
    float lmax = -3.4e38f;
    for(int q = lane; q < cn; q += 64){
      float2 ws = lw[r0 + c0 + q];
      s_ws[wid][q] = ws;
      lmax = fmaxf(lmax, ws.x);
    }
    #pragma unroll
    for(int o = 32; o; o >>= 1) lmax = fmaxf(lmax, __shfl_xor(lmax, o));
    float newm = fmaxf(m, lmax);
    float scale = expf(m - newm);
    denom *= scale;
    #pragma unroll
    for(int j = 0; j < JMAX; ++j) acc[j] *= scale;
    m = newm;
    float psum = 0.0f;
    for(int q = lane; q < cn; q += 64){
      float2 ws = s_ws[wid][q];
      float w = expf(ws.x - m);
      s_ws[wid][q].x = w;
      psum += w;
    }
    #pragma unroll
    for(int o = 32; o; o >>= 1) psum += __shfl_xor(psum, o);
    denom += psum;
    int p = 0;
    for(; p + 4 <= cn; p += 4){
      float2 w0 = s_ws[wid][p + 0];
      float2 w1 = s_ws[wid][p + 1];
      float2 w2 = s_ws[wid][p + 2];
      float2 w3 = s_ws[wid][p + 3];
      const float* x0 = xl + (long)__float_as_int(w0.y) * F;
      const float* x1 = xl + (long)__float_as_int(w1.y) * F;
      const float* x2 = xl + (long)__float_as_int(w2.y) * F;
      const float* x3 = xl + (long)__float_as_int(w3.y) * F;
      float v0[JMAX], v1[JMAX], v2[JMAX], v3[JMAX];
      #pragma unroll
      for(int j = 0; j < JMAX; ++j){
        int f = lane + j * 64; bool okf = f < F;
        v0[j] = okf ? x0[f] : 0.0f;
        v1[j] = okf ? x1[f] : 0.0f;
        v2[j] = okf ? x2[f] : 0.0f;
        v3[j] = okf ? x3[f] : 0.0f;
      }
      #pragma unroll
      for(int j = 0; j < JMAX; ++j){
        acc[j] = fmaf(w0.x, v0[j], acc[j]);
        acc[j] = fmaf(w1.x, v1[j], acc[j]);
        acc[j] = fmaf(w2.x, v2[j], acc[j]);
        acc[j] = fmaf(w3.x, v3[j], acc[j]);
      }
    }
    for(; p < cn; ++p){
      float2 ws = s_ws[wid][p];
      const float* xs = xl + (long)__float_as_int(ws.y) * F;
      #pragma unroll
      for(int j = 0; j < JMAX; ++j){
        int f = lane + j * 64;
        if(f < F) acc[j] = fmaf(ws.x, xs[f], acc[j]);
      }
    }
  }

  float inv = 1.0f / denom;
  #pragma unroll
  for(int j = 0; j < JMAX; ++j){
    int f = lane + j * 64;
    if(f < F){
      float o = acc[j] * inv + bias[f];
      out[(long)i * F + f] = dorelu ? fmaxf(o, 0.0f) : o;
    }
  }
}

// ===================== rule pooling (rule_batch sorted) =====================
__global__ void k_rule_starts(const int* __restrict__ rb, int* starts, int NR, int R){
  int r = blockIdx.x * blockDim.x + threadIdx.x;
  if(r > R) return;
  if(r == R){ starts[R] = NR; return; }
  int lo = 0, hi = NR;
  while(lo < hi){ int mid = (lo + hi) >> 1; if(rb[mid] < r) lo = mid + 1; else hi = mid; }
  starts[r] = lo;
}

__global__ void k_pool_rules(const float* __restrict__ h, const int* __restrict__ starts,
                             float* __restrict__ y, int R, int F){
  long idx = (long)blockIdx.x * blockDim.x + threadIdx.x;
  long total = (long)R * F;
  if(idx >= total) return;
  int r = (int)(idx / F);
  int f = (int)(idx % F);
  int s0 = starts[r], s1 = starts[r + 1];
  float a = 0.0f;
  for(int i = s0; i < s1; i++) a += h[(long)i * F + f];
  y[idx] = a / fmaxf((float)(s1 - s0), 1.0f);
}

// ===================== global mean (register accumulate, no LDS atomics) =====================
// One wave per row-stripe; lane l sums features l and l+64 across its rows
// (coalesced 400B row reads, zero atomics in the loop). Cross-wave LDS reduce,
// then one global atomicAdd of F floats per block.
__global__ __launch_bounds__(256) void k_pool_all(
    const float* __restrict__ g, float* xp, int n, int F)
{
  const int lane = threadIdx.x & 63;
  const int wid  = threadIdx.x >> 6;
  const int nw   = 4;
  float a0 = 0.0f, a1 = 0.0f;
  const bool ok0 = lane < F, ok1 = lane + 64 < F;
  for(int r = blockIdx.x * nw + wid; r < n; r += gridDim.x * nw){
    const float* row = g + (long)r * F;
    if(ok0) a0 += row[lane];
    if(ok1) a1 += row[lane + 64];
  }
  __shared__ float s[4][128];
  s[wid][lane] = a0;
  s[wid][lane + 64] = a1;
  __syncthreads();
  if(wid == 0){
    float t0 = s[0][lane] + s[1][lane] + s[2][lane] + s[3][lane];
    float t1 = s[0][lane + 64] + s[1][lane + 64] + s[2][lane + 64] + s[3][lane + 64];
    if(ok0 && t0 != 0.0f) atomicAdd(&xp[lane], t0);
    if(ok1 && t1 != 0.0f) atomicAdd(&xp[lane + 64], t1);
  }
}

__global__ void k_bil_v(const float* __restrict__ xp, const float* __restrict__ Wb,
                        float* v, float inv_n){
  int e = threadIdx.x;
  if(e < 100){
    float a = 0.0f;
    for(int d = 0; d < 100; d++) a += xp[d] * Wb[d * 100 + e];
    v[e] = a * inv_n;
  }
}

__global__ void k_bil_out(const float* __restrict__ v, const float* __restrict__ y,
                          const float* __restrict__ bilb, float* out, int R){
  int r = blockIdx.x * blockDim.x + threadIdx.x;
  if(r < R){
    float a = 0.0f;
    const float* yr = y + (long)r * 100;
    for(int e = 0; e < 100; e++) a += v[e] * yr[e];
    out[r] = a + bilb[0];
  }
}

// ------------------------------------------------------------------
static inline int nblk(long n){
  long b = (n + 255) / 256;
  if(b > 20480) b = 20480;
  if(b < 1) b = 1;
  return (int)b;
}

struct GatParams { const float *Wl,*bl,*Wr,*br,*We,*att,*b; };

template<int G, int F, bool SELF>
static void logits_launch(const float* xl, const float* xr, const float* ea,
                          const int* src, const int* dst, const int* eidx,
                          const float* We, const float* att, float2* lw, float* slf,
                          int E, hipStream_t stream){
  const int epb = (256 / G) * 4;   // items per block-iteration
  long nb = ((long)E + epb - 1) / epb;
  int grid = (int)(nb < 2048 ? nb : 2048);
  k_edge_logits<G, F, SELF><<<grid, 256, 0, stream>>>(xl, xr, ea, src, dst, eidx,
                                                      We, att, lw, slf, E);
}

static void run_gatv2(const float* x, int fin, int fout, int n,
                      const int* src, const int* dst, const float* ea, int E,
                      GatParams P, float* out, int dorelu,
                      float* xl, float* xr, float2* lw, float* selfl,
                      const float* eam, const int* rowoff, const int* eidx,
                      hipStream_t stream){
  gemm_launch(x, P.Wl, P.bl, xl, n, fin, fout, 0, stream);
  gemm_launch(x, P.Wr, P.br, xr, n, fin, fout, 0, stream);
  if(fout == 100){
    logits_launch<32, 100, false>(xl, xr, ea, src, dst, eidx, P.We, P.att, lw, nullptr, E, stream);
    logits_launch<32, 100, true >(xl, xr, eam, nullptr, nullptr, nullptr, P.We, P.att, nullptr, selfl, n, stream);
    k_gat_agg<2><<<(n + 3) / 4, 256, 0, stream>>>(xl, rowoff, lw, selfl, P.b, out, n, fout, dorelu);
  } else {
    logits_launch<64, 200, false>(xl, xr, ea, src, dst, eidx, P.We, P.att, lw, nullptr, E, stream);
    logits_launch<64, 200, true >(xl, xr, eam, nullptr, nullptr, nullptr, P.We, P.att, nullptr, selfl, n, stream);
    k_gat_agg<4><<<(n + 3) / 4, 256, 0, stream>>>(xl, rowoff, lw, selfl, P.b, out, n, fout, dorelu);
  }
}

extern "C" void kernel_launch(void* const* d_in, const int* in_sizes, int n_in,
                              void* d_out, int out_size, void* d_ws, size_t ws_size,
                              hipStream_t stream){
  const float* x   = (const float*)d_in[0];
  const float* ea  = (const float*)d_in[1];
  const float* rx  = (const float*)d_in[2];
  const float* rea = (const float*)d_in[3];
  GatParams g0{ (const float*)d_in[4],  (const float*)d_in[5],  (const float*)d_in[6],
                (const float*)d_in[7],  (const float*)d_in[8],  (const float*)d_in[9],
                (const float*)d_in[10] };
  GatParams g1{ (const float*)d_in[11], (const float*)d_in[12], (const float*)d_in[13],
                (const float*)d_in[14], (const float*)d_in[15], (const float*)d_in[16],
                (const float*)d_in[17] };
  GatParams g2{ (const float*)d_in[18], (const float*)d_in[19], (const float*)d_in[20],
                (const float*)d_in[21], (const float*)d_in[22], (const float*)d_in[23],
                (const float*)d_in[24] };
  const float* lin_W = (const float*)d_in[25]; const float* lin_b = (const float*)d_in[26];
  const float* f1_W  = (const float*)d_in[27]; const float* f1_b  = (const float*)d_in[28];
  const float* f2_W  = (const float*)d_in[29]; const float* f2_b  = (const float*)d_in[30];
  const float* f3_W  = (const float*)d_in[31]; const float* f3_b  = (const float*)d_in[32];
  const float* bilW  = (const float*)d_in[33]; const float* bilb  = (const float*)d_in[34];
  const int* ei  = (const int*)d_in[35];
  const int* rei = (const int*)d_in[37];
  const int* rb  = (const int*)d_in[38];

  const int N  = in_sizes[0] / 16;
  const int E  = in_sizes[1] / 18;
  const int NR = in_sizes[2] / 16;
  const int ER = in_sizes[3] / 18;
  const int R  = out_size;

  float* Wf = (float*)d_ws;
  size_t off = 0;
  auto alloc  = [&](size_t nf){ nf = (nf + 1) & ~(size_t)1; float* p = Wf + off; off += nf; return p; };
  auto alloci = [&](size_t ni){ ni = (ni + 1) & ~(size_t)1; int* p = (int*)(Wf + off); off += ni; return p; };

  // persistent head
  float* y0 = alloc((size_t)R * 400);
  float* y1 = alloc((size_t)R * 200);
  float* y2 = alloc((size_t)R * 100);
  float* y3 = alloc((size_t)R * 100);
  float* xp = alloc(128);
  float* v  = alloc(128);
  int* starts = alloci(R + 1);
  const size_t arena = off;

  // ================= rule path =================
  {
    off = arena;
    float* h1 = alloc((size_t)NR * 100);
    float* h2 = alloc((size_t)NR * 200);
    float* xl = alloc((size_t)NR * 200);
    float* xr = alloc((size_t)NR * 200);
    float2* lw = (float2*)alloc((size_t)ER * 2);
    float* eam   = alloc((size_t)NR * 18);
    float* selfl = alloc(NR);
    int* rowoff = alloci(NR + 1);
    int* degi   = alloci(NR);
    int* pos    = alloci(NR);
    int* eidx   = alloci(ER);
    const int* rsrc = rei; const int* rdst = rei + ER;

    hipMemsetAsync(degi, 0, (size_t)NR * 4, stream);
    k_deg<<<nblk(ER), 256, 0, stream>>>(rdst, degi, ER);
    k_scan<<<1, 1024, 0, stream>>>(degi, rowoff, NR);
    hipMemcpyAsync(pos, rowoff, (size_t)NR * 4, hipMemcpyDeviceToDevice, stream);
    k_fill<<<nblk(ER), 256, 0, stream>>>(rdst, pos, eidx, ER);
    k_easum<<<(NR + 3) / 4, 256, 0, stream>>>(rea, rowoff, eidx, eam, NR);

    run_gatv2(rx, 16, 100, NR, rsrc, rdst, rea, ER, g1, h1, 1,
              xl, xr, lw, selfl, eam, rowoff, eidx, stream);
    run_gatv2(h1, 100, 200, NR, rsrc, rdst, rea, ER, g2, h2, 1,
              xl, xr, lw, selfl, eam, rowoff, eidx, stream);

    float* hlin = xl;  // NR*400 floats (xl+xr contiguous)
    gemm_launch(h2, lin_W, lin_b, hlin, NR, 200, 400, 0, stream);

    k_rule_starts<<<(R + 256) / 256, 256, 0, stream>>>(rb, starts, NR, R);
    k_pool_rules<<<nblk((long)R * 400), 256, 0, stream>>>(hlin, starts, y0, R, 400);

    gemm_launch(y0, f1_W, f1_b, y1, R, 400, 200, 1, stream);
    gemm_launch(y1, f2_W, f2_b, y2, R, 200, 100, 1, stream);
    gemm_launch(y2, f3_W, f3_b, y3, R, 100, 100, 0, stream);
  }

  // ================= data path =================
  {
    off = arena;
    float* g  = alloc((size_t)N * 100);
    float* xl = alloc((size_t)N * 100);
    float* xr = alloc((size_t)N * 100);
    float2* lw = (float2*)alloc((size_t)E * 2);
    float* eam   = alloc((size_t)N * 18);
    float* selfl = alloc(N);
    int* rowoff = alloci((size_t)N + 1);
    int* degi   = alloci(N);
    int* pos    = alloci(N);
    int* eidx   = alloci(E);
    const int* srcp = ei; const int* dstp = ei + E;

    hipMemsetAsync(degi, 0, (size_t)N * 4, stream);
    k_deg<<<nblk(E), 256, 0, stream>>>(dstp, degi, E);
    k_scan<<<1, 1024, 0, stream>>>(degi, rowoff, N);
    hipMemcpyAsync(pos, rowoff, (size_t)N * 4, hipMemcpyDeviceToDevice, stream);
    k_fill<<<nblk(E), 256, 0, stream>>>(dstp, pos, eidx, E);
    k_easum<<<(N + 3) / 4, 256, 0, stream>>>(ea, rowoff, eidx, eam, N);

    run_gatv2(x, 16, 100, N, srcp, dstp, ea, E, g0, g, 0,
              xl, xr, lw, selfl, eam, rowoff, eidx, stream);

    hipMemsetAsync(xp, 0, 128 * 4, stream);
    k_pool_all<<<1024, 256, 0, stream>>>(g, xp, N, 100);
    k_bil_v<<<1, 128, 0, stream>>>(xp, bilW, v, 1.0f / (float)N);
    k_bil_out<<<(R + 127) / 128, 128, 0, stream>>>(v, y3, bilb, (float*)d_out, R);
  }
}

// Round 9
// 1116.106 us; speedup vs baseline: 2.3898x; 1.0605x over previous
//
#include <hip/hip_runtime.h>

#define NS 0.2f  // leaky_relu negative slope

// ===================== CSR construction =====================
__global__ void k_deg(const int* __restrict__ dst, int* degi, int E){
  int stride = gridDim.x * blockDim.x;
  for(int e = blockIdx.x * blockDim.x + threadIdx.x; e < E; e += stride)
    atomicAdd(&degi[dst[e]], 1);
}

__device__ __forceinline__ int wave_iscan(int v, int lane){
  #pragma unroll
  for(int o = 1; o < 64; o <<= 1){
    int t = __shfl_up(v, o);
    if(lane >= o) v += t;
  }
  return v;
}

// ---- 3-phase multi-block exclusive scan (replaces single-block k_scan) ----
// Phase A: per-block sum of a 1024 chunk -> bsum[b]
__global__ __launch_bounds__(1024) void k_scan_sum(
    const int* __restrict__ deg, int* __restrict__ bsum, int n)
{
  __shared__ int wsum[16];
  const int lane = threadIdx.x & 63;
  const int w = threadIdx.x >> 6;
  int idx = blockIdx.x * 1024 + threadIdx.x;
  int v = (idx < n) ? deg[idx] : 0;
  #pragma unroll
  for(int o = 32; o; o >>= 1) v += __shfl_xor(v, o);
  if(lane == 0) wsum[w] = v;
  __syncthreads();
  if(w == 0){
    int s = (lane < 16) ? wsum[lane] : 0;
    #pragma unroll
    for(int o = 8; o; o >>= 1) s += __shfl_xor(s, o);
    if(lane == 0) bsum[blockIdx.x] = s;
  }
}

// Phase B: single block (<=128 partials) exclusive-scans bsum in place; writes rowoff[n]=total
__global__ __launch_bounds__(128) void k_scan_bsum(
    int* __restrict__ bsum, int* __restrict__ rowoff, int B, int n)
{
  __shared__ int wtot[2];
  const int lane = threadIdx.x & 63;
  const int w = threadIdx.x >> 6;
  int t = threadIdx.x;
  int v = (t < B) ? bsum[t] : 0;
  int inc = wave_iscan(v, lane);
  if(lane == 63) wtot[w] = inc;
  __syncthreads();
  int off = (w > 0) ? wtot[0] : 0;
  if(t < B) bsum[t] = off + inc - v;   // exclusive
  if(t == 0) rowoff[n] = wtot[0] + wtot[1];
}

// Phase C: per-block exclusive scan + bsum offset; writes rowoff and pos
__global__ __launch_bounds__(1024) void k_scan_apply(
    const int* __restrict__ deg, const int* __restrict__ bsum,
    int* __restrict__ rowoff, int* __restrict__ pos, int n)
{
  __shared__ int wsum[16];
  const int lane = threadIdx.x & 63;
  const int w = threadIdx.x >> 6;
  int idx = blockIdx.x * 1024 + threadIdx.x;
  int v = (idx < n) ? deg[idx] : 0;
  int inc = wave_iscan(v, lane);
  if(lane == 63) wsum[w] = inc;
  __syncthreads();
  if(w == 0){
    int s = (lane < 16) ? wsum[lane] : 0;
    s = wave_iscan(s, lane);
    if(lane < 16) wsum[lane] = s;
  }
  __syncthreads();
  int woff = (w > 0) ? wsum[w - 1] : 0;
  if(idx < n){
    int ex = bsum[blockIdx.x] + woff + inc - v;
    rowoff[idx] = ex;
    pos[idx] = ex;
  }
}

__global__ void k_fill(const int* __restrict__ dst, int* pos, int* eidx, int E){
  int stride = gridDim.x * blockDim.x;
  for(int e = blockIdx.x * blockDim.x + threadIdx.x; e < E; e += stride){
    int slot = atomicAdd(&pos[dst[e]], 1);
    eidx[slot] = e;
  }
}

// ===================== ea_mean per node (lane-parallel, no dependent chain) =====================
__global__ __launch_bounds__(256) void k_easum(
    const float* __restrict__ ea, const int* __restrict__ rowoff,
    const int* __restrict__ eidx, float* __restrict__ eam, int n)
{
  const int lane = threadIdx.x & 63;
  const int wid  = threadIdx.x >> 6;
  const int i = blockIdx.x * 4 + wid;
  if(i >= n) return;
  const int r0 = rowoff[i], r1 = rowoff[i + 1];
  const int deg = r1 - r0;
  const int pg = lane / 18;          // 0..3 (group 3 idle)
  const int k  = lane - pg * 18;
  float s = 0.0f;
  if(pg < 3){
    for(int p = r0 + pg; p < r1; p += 3)
      s += ea[(long)eidx[p] * 18 + k];
  }
  float b = __shfl(s, lane + 18);
  float c = __shfl(s, lane + 36);
  if(lane < 18) eam[(long)i * 18 + lane] = (s + b + c) / fmaxf((float)deg, 1.0f);
}

// ===================== tiled GEMM: C = A @ W^T + b =====================
#define BM 64
#define BN 64
#define BK 16
__global__ __launch_bounds__(256) void k_gemm(
    const float* __restrict__ A, const float* __restrict__ W,
    const float* __restrict__ b, float* __restrict__ C,
    int n, int K, int M, int dorelu)
{
  __shared__ float As[BM][BK + 1];
  __shared__ float Bs[BN][BK + 1];
  const int bi = blockIdx.x * BM;
  const int bj = blockIdx.y * BN;
  const int tid = threadIdx.x;
  const int tr = tid / 16, tc = tid % 16;
  float acc[4][4] = {};
  for(int k0 = 0; k0 < K; k0 += BK){
    for(int l = tid; l < BM * BK; l += 256){
      int r = l / BK, c = l % BK;
      int gr = bi + r, gc = k0 + c;
      As[r][c] = (gr < n && gc < K) ? A[(long)gr * K + gc] : 0.0f;
    }
    for(int l = tid; l < BN * BK; l += 256){
      int r = l / BK, c = l % BK;
      int gr = bj + r, gc = k0 + c;
      Bs[r][c] = (gr < M && gc < K) ? W[(long)gr * K + gc] : 0.0f;
    }
    __syncthreads();
    #pragma unroll
    for(int kk = 0; kk < BK; ++kk){
      float av[4], bv[4];
      #pragma unroll
      for(int r = 0; r < 4; r++) av[r] = As[tr * 4 + r][kk];
      #pragma unroll
      for(int c = 0; c < 4; c++) bv[c] = Bs[tc * 4 + c][kk];
      #pragma unroll
      for(int r = 0; r < 4; r++)
        #pragma unroll
        for(int c = 0; c < 4; c++) acc[r][c] += av[r] * bv[c];
    }
    __syncthreads();
  }
  for(int r = 0; r < 4; r++){
    int gr = bi + tr * 4 + r;
    if(gr >= n) continue;
    for(int c = 0; c < 4; c++){
      int gc = bj + tc * 4 + c;
      if(gc >= M) continue;
      float val = acc[r][c] + b[gc];
      C[(long)gr * M + gc] = dorelu ? fmaxf(val, 0.0f) : val;
    }
  }
}

static void gemm_launch(const float* A, const float* W, const float* b, float* C,
                        int n, int K, int M, int relu, hipStream_t s){
  dim3 grid((n + BM - 1) / BM, (M + BN - 1) / BN);
  k_gemm<<<grid, 256, 0, s>>>(A, W, b, C, n, K, M, relu);
}

__device__ __forceinline__ float lkrelu(float t){ return (t > 0.0f) ? t : NS * t; }

// ===================== logits: G-lane group x NE=4 items, persistent blocks =====================
template<int G, int F, bool SELF>
__global__ __launch_bounds__(256) void k_edge_logits(
    const float* __restrict__ xl, const float* __restrict__ xr,
    const float* __restrict__ ea,
    const int* __restrict__ src, const int* __restrict__ dst,
    const int* __restrict__ eidx,
    const float* __restrict__ We, const float* __restrict__ att,
    float2* __restrict__ lw, float* __restrict__ slf, int E)
{
  constexpr int NG = 256 / G;       // groups per block
  constexpr int NE = 4;             // items per group-iteration
  constexpr int FQ = F / 4;         // float4s per feature row
  __shared__ float4 sWeT[18 * FQ];  // [k][f4], transposed
  __shared__ float4 sAtt[FQ];
  __shared__ float4 sEa[NG][18];    // [k] -> (ea_e0, ea_e1, ea_e2, ea_e3)
  __shared__ int    sIdx[NG][3][NE];// [0]=e, [1]=src, [2]=dst

  const int tid = threadIdx.x;
  for(int idx = tid; idx < F * 18; idx += 256){
    int f = idx / 18, k = idx % 18;            // coalesced global read
    ((float*)sWeT)[k * F + f] = We[idx];
  }
  for(int f = tid; f < F; f += 256) ((float*)sAtt)[f] = att[f];
  __syncthreads();

  const int g  = tid / G;
  const int gl = tid % G;
  const bool act = (gl * 4 < F);
  const int glc = act ? gl : 0;
  const long step = (long)gridDim.x * (NG * NE);

  for(long base = (long)blockIdx.x * (NG * NE); base < (long)E; base += step){
    const long pb = base + (long)g * NE;
    if(gl < NE){
      long p = pb + gl;
      int e = -1, s = 0, d = 0;
      if(p < (long)E){
        if(SELF){ e = (int)p; s = e; d = e; }
        else    { e = eidx[p]; s = src[e]; d = dst[e]; }
      }
      sIdx[g][0][gl] = e; sIdx[g][1][gl] = s; sIdx[g][2][gl] = d;
    }
    // stage 4 ea rows as float2 (72B rows are 8B-aligned) -> half the VMEM ops
    #pragma unroll
    for(int t = 0; t < (9 * NE + G - 1) / G; ++t){
      int u = t * G + gl;
      if(u < 9 * NE){
        int ne = u & 3, k2 = u >> 2;
        int e = sIdx[g][0][ne];
        float2 v = (e >= 0) ? *(const float2*)(ea + (long)e * 18 + k2 * 2)
                            : make_float2(0.0f, 0.0f);
        ((float*)&sEa[g][k2 * 2 + 0])[ne] = v.x;
        ((float*)&sEa[g][k2 * 2 + 1])[ne] = v.y;
      }
    }
    int4 sv = *(const int4*)&sIdx[g][1][0];
    int4 dv = *(const int4*)&sIdx[g][2][0];
    float4 a0 = *(const float4*)(xl + (long)sv.x * F + glc * 4);
    float4 b0 = *(const float4*)(xr + (long)dv.x * F + glc * 4);
    float4 a1 = *(const float4*)(xl + (long)sv.y * F + glc * 4);
    float4 b1 = *(const float4*)(xr + (long)dv.y * F + glc * 4);
    float4 a2 = *(const float4*)(xl + (long)sv.z * F + glc * 4);
    float4 b2 = *(const float4*)(xr + (long)dv.z * F + glc * 4);
    float4 a3 = *(const float4*)(xl + (long)sv.w * F + glc * 4);
    float4 b3 = *(const float4*)(xr + (long)dv.w * F + glc * 4);
    float4 t0 = make_float4(a0.x + b0.x, a0.y + b0.y, a0.z + b0.z, a0.w + b0.w);
    float4 t1 = make_float4(a1.x + b1.x, a1.y + b1.y, a1.z + b1.z, a1.w + b1.w);
    float4 t2 = make_float4(a2.x + b2.x, a2.y + b2.y, a2.z + b2.z, a2.w + b2.w);
    float4 t3 = make_float4(a3.x + b3.x, a3.y + b3.y, a3.z + b3.z, a3.w + b3.w);
    #pragma unroll
    for(int k = 0; k < 18; ++k){
      float4 w  = sWeT[k * FQ + glc];
      float4 eq = sEa[g][k];
      t0.x = fmaf(w.x, eq.x, t0.x); t0.y = fmaf(w.y, eq.x, t0.y);
      t0.z = fmaf(w.z, eq.x, t0.z); t0.w = fmaf(w.w, eq.x, t0.w);
      t1.x = fmaf(w.x, eq.y, t1.x); t1.y = fmaf(w.y, eq.y, t1.y);
      t1.z = fmaf(w.z, eq.y, t1.z); t1.w = fmaf(w.w, eq.y, t1.w);
      t2.x = fmaf(w.x, eq.z, t2.x); t2.y = fmaf(w.y, eq.z, t2.y);
      t2.z = fmaf(w.z, eq.z, t2.z); t2.w = fmaf(w.w, eq.z, t2.w);
      t3.x = fmaf(w.x, eq.w, t3.x); t3.y = fmaf(w.y, eq.w, t3.y);
      t3.z = fmaf(w.z, eq.w, t3.z); t3.w = fmaf(w.w, eq.w, t3.w);
    }
    float4 av = sAtt[glc];
    float r0 = 0, r1 = 0, r2 = 0, r3 = 0;
    if(act){
      r0 = av.x * lkrelu(t0.x) + av.y * lkrelu(t0.y) + av.z * lkrelu(t0.z) + av.w * lkrelu(t0.w);
      r1 = av.x * lkrelu(t1.x) + av.y * lkrelu(t1.y) + av.z * lkrelu(t1.z) + av.w * lkrelu(t1.w);
      r2 = av.x * lkrelu(t2.x) + av.y * lkrelu(t2.y) + av.z * lkrelu(t2.z) + av.w * lkrelu(t2.w);
      r3 = av.x * lkrelu(t3.x) + av.y * lkrelu(t3.y) + av.z * lkrelu(t3.z) + av.w * lkrelu(t3.w);
    }
    #pragma unroll
    for(int o = G / 2; o; o >>= 1){
      r0 += __shfl_xor(r0, o);
      r1 += __shfl_xor(r1, o);
      r2 += __shfl_xor(r2, o);
      r3 += __shfl_xor(r3, o);
    }
    if(SELF){
      if(gl == 0 && pb + 0 < (long)E) slf[pb + 0] = r0;
      if(gl == 1 && pb + 1 < (long)E) slf[pb + 1] = r1;
      if(gl == 2 && pb + 2 < (long)E) slf[pb + 2] = r2;
      if(gl == 3 && pb + 3 < (long)E) slf[pb + 3] = r3;
    } else {
      if(gl == 0 && pb + 0 < (long)E) lw[pb + 0] = make_float2(r0, __int_as_float(sv.x));
      if(gl == 1 && pb + 1 < (long)E) lw[pb + 1] = make_float2(r1, __int_as_float(sv.y));
      if(gl == 2 && pb + 2 < (long)E) lw[pb + 2] = make_float2(r2, __int_as_float(sv.z));
      if(gl == 3 && pb + 3 < (long)E) lw[pb + 3] = make_float2(r3, __int_as_float(sv.w));
    }
  }
}

// ===================== node softmax + aggregate: one WAVE per node =====================
#define CH 128
template<int JMAX>
__global__ __launch_bounds__(256) void k_gat_agg(
    const float* __restrict__ xl,
    const int* __restrict__ rowoff,
    const float2* __restrict__ lw, const float* __restrict__ selfl,
    const float* __restrict__ bias, float* __restrict__ out,
    int n, int F, int dorelu)
{
  const int lane = threadIdx.x & 63;
  const int wid  = threadIdx.x >> 6;
  __shared__ float2 s_ws[4][CH];   // {weight, src bits}
  const int i = blockIdx.x * 4 + wid;
  if(i >= n) return;          // wave-uniform exit; no __syncthreads below
  const int r0 = rowoff[i], r1 = rowoff[i + 1];
  const int deg = r1 - r0;

  float m = selfl[i], denom = 1.0f;
  float acc[JMAX];
  #pragma unroll
  for(int j = 0; j < JMAX; ++j){
    int f = lane + j * 64;
    acc[j] = (f < F) ? xl[(long)i * F + f] : 0.0f;
  }

  for(int c0 = 0; c0 < deg; c0 += CH){
    int cn = min(CH, deg - c0);
    float lmax = -3.4e38f;
    for(int q = lane; q < cn; q += 64){
      float2 ws = lw[r0 + c0 + q];
      s_ws[wid][q] = ws;
      lmax = fmaxf(lmax, ws.x);
    }
    #pragma unroll
    for(int o = 32; o; o >>= 1) lmax = fmaxf(lmax, __shfl_xor(lmax, o));
    float newm = fmaxf(m, lmax);
    float scale = __expf(m - newm);
    denom *= scale;
    #pragma unroll
    for(int j = 0; j < JMAX; ++j) acc[j] *= scale;
    m = newm;
    float psum = 0.0f;
    for(int q = lane; q < cn; q += 64){
      float2 ws = s_ws[wid][q];
      float w = __expf(ws.x - m);
      s_ws[wid][q].x = w;
      psum += w;
    }
    #pragma unroll
    for(int o = 32; o; o >>= 1) psum += __shfl_xor(psum, o);
    denom += psum;
    // gather-aggregate, 8 edges in flight
    int p = 0;
    for(; p + 8 <= cn; p += 8){
      float2 wv[8];
      const float* xs[8];
      #pragma unroll
      for(int u = 0; u < 8; ++u){
        wv[u] = s_ws[wid][p + u];
        xs[u] = xl + (long)__float_as_int(wv[u].y) * F;
      }
      float vv[8][JMAX];
      #pragma unroll
      for(int u = 0; u < 8; ++u)
        #pragma unroll
        for(int j = 0; j < JMAX; ++j){
          int f = lane + j * 64;
          vv[u][j] = (f < F) ? xs[u][f] : 0.0f;
        }
      #pragma unroll
      for(int u = 0; u < 8; ++u)
        #pragma unroll
        for(int j = 0; j < JMAX; ++j)
          acc[j] = fmaf(wv[u].x, vv[u][j], acc[j]);
    }
    for(; p < cn; ++p){
      float2 ws = s_ws[wid][p];
      const float* xs = xl + (long)__float_as_int(ws.y) * F;
      #pragma unroll
      for(int j = 0; j < JMAX; ++j){
        int f = lane + j * 64;
        if(f < F) acc[j] = fmaf(ws.x, xs[f], acc[j]);
      }
    }
  }

  float inv = 1.0f / denom;
  #pragma unroll
  for(int j = 0; j < JMAX; ++j){
    int f = lane + j * 64;
    if(f < F){
      float o = acc[j] * inv + bias[f];
      out[(long)i * F + f] = dorelu ? fmaxf(o, 0.0f) : o;
    }
  }
}

// ===================== rule pooling (rule_batch sorted) =====================
__global__ void k_rule_starts(const int* __restrict__ rb, int* starts, int NR, int R){
  int r = blockIdx.x * blockDim.x + threadIdx.x;
  if(r > R) return;
  if(r == R){ starts[R] = NR; return; }
  int lo = 0, hi = NR;
  while(lo < hi){ int mid = (lo + hi) >> 1; if(rb[mid] < r) lo = mid + 1; else hi = mid; }
  starts[r] = lo;
}

__global__ void k_pool_rules(const float* __restrict__ h, const int* __restrict__ starts,
                             float* __restrict__ y, int R, int F){
  long idx = (long)blockIdx.x * blockDim.x + threadIdx.x;
  long total = (long)R * F;
  if(idx >= total) return;
  int r = (int)(idx / F);
  int f = (int)(idx % F);
  int s0 = starts[r], s1 = starts[r + 1];
  float a = 0.0f;
  for(int i = s0; i < s1; i++) a += h[(long)i * F + f];
  y[idx] = a / fmaxf((float)(s1 - s0), 1.0f);
}

// ===================== global mean (register accumulate, no LDS atomics) =====================
__global__ __launch_bounds__(256) void k_pool_all(
    const float* __restrict__ g, float* xp, int n, int F)
{
  const int lane = threadIdx.x & 63;
  const int wid  = threadIdx.x >> 6;
  const int nw   = 4;
  float a0 = 0.0f, a1 = 0.0f;
  const bool ok0 = lane < F, ok1 = lane + 64 < F;
  for(int r = blockIdx.x * nw + wid; r < n; r += gridDim.x * nw){
    const float* row = g + (long)r * F;
    if(ok0) a0 += row[lane];
    if(ok1) a1 += row[lane + 64];
  }
  __shared__ float s[4][128];
  s[wid][lane] = a0;
  s[wid][lane + 64] = a1;
  __syncthreads();
  if(wid == 0){
    float t0 = s[0][lane] + s[1][lane] + s[2][lane] + s[3][lane];
    float t1 = s[0][lane + 64] + s[1][lane + 64] + s[2][lane + 64] + s[3][lane + 64];
    if(ok0 && t0 != 0.0f) atomicAdd(&xp[lane], t0);
    if(ok1 && t1 != 0.0f) atomicAdd(&xp[lane + 64], t1);
  }
}

// ===================== fused bilinear head: out[r] = bilb + (xp/N·Wb)·y3[r] =====================
__global__ __launch_bounds__(512) void k_bil(
    const float* __restrict__ xp, const float* __restrict__ Wb,
    const float* __restrict__ y, const float* __restrict__ bilb,
    float* __restrict__ out, float inv_n, int R)
{
  __shared__ float v[100];
  int t = threadIdx.x;
  if(t < 100){
    float a = 0.0f;
    for(int d = 0; d < 100; d++) a += xp[d] * Wb[d * 100 + t];
    v[t] = a * inv_n;
  }
  __syncthreads();
  for(int r = t; r < R; r += 512){
    float a = 0.0f;
    const float* yr = y + (long)r * 100;
    for(int e = 0; e < 100; e++) a += v[e] * yr[e];
    out[r] = a + bilb[0];
  }
}

// ------------------------------------------------------------------
static inline int nblk(long n){
  long b = (n + 255) / 256;
  if(b > 20480) b = 20480;
  if(b < 1) b = 1;
  return (int)b;
}

struct GatParams { const float *Wl,*bl,*Wr,*br,*We,*att,*b; };

template<int G, int F, bool SELF>
static void logits_launch(const float* xl, const float* xr, const float* ea,
                          const int* src, const int* dst, const int* eidx,
                          const float* We, const float* att, float2* lw, float* slf,
                          int E, hipStream_t stream){
  const int epb = (256 / G) * 4;   // items per block-iteration
  long nb = ((long)E + epb - 1) / epb;
  int grid = (int)(nb < 2048 ? nb : 2048);
  k_edge_logits<G, F, SELF><<<grid, 256, 0, stream>>>(xl, xr, ea, src, dst, eidx,
                                                      We, att, lw, slf, E);
}

// multi-block CSR offsets: deg -> rowoff (exclusive) + pos copy
static void scan_launch(const int* degi, int* bsum, int* rowoff, int* pos,
                        int n, hipStream_t stream){
  int B = (n + 1023) / 1024;
  k_scan_sum  <<<B, 1024, 0, stream>>>(degi, bsum, n);
  k_scan_bsum <<<1, 128,  0, stream>>>(bsum, rowoff, B, n);
  k_scan_apply<<<B, 1024, 0, stream>>>(degi, bsum, rowoff, pos, n);
}

static void run_gatv2(const float* x, int fin, int fout, int n,
                      const int* src, const int* dst, const float* ea, int E,
                      GatParams P, float* out, int dorelu,
                      float* xl, float* xr, float2* lw, float* selfl,
                      const float* eam, const int* rowoff, const int* eidx,
                      hipStream_t stream){
  gemm_launch(x, P.Wl, P.bl, xl, n, fin, fout, 0, stream);
  gemm_launch(x, P.Wr, P.br, xr, n, fin, fout, 0, stream);
  if(fout == 100){
    logits_launch<32, 100, false>(xl, xr, ea, src, dst, eidx, P.We, P.att, lw, nullptr, E, stream);
    logits_launch<32, 100, true >(xl, xr, eam, nullptr, nullptr, nullptr, P.We, P.att, nullptr, selfl, n, stream);
    k_gat_agg<2><<<(n + 3) / 4, 256, 0, stream>>>(xl, rowoff, lw, selfl, P.b, out, n, fout, dorelu);
  } else {
    logits_launch<64, 200, false>(xl, xr, ea, src, dst, eidx, P.We, P.att, lw, nullptr, E, stream);
    logits_launch<64, 200, true >(xl, xr, eam, nullptr, nullptr, nullptr, P.We, P.att, nullptr, selfl, n, stream);
    k_gat_agg<4><<<(n + 3) / 4, 256, 0, stream>>>(xl, rowoff, lw, selfl, P.b, out, n, fout, dorelu);
  }
}

extern "C" void kernel_launch(void* const* d_in, const int* in_sizes, int n_in,
                              void* d_out, int out_size, void* d_ws, size_t ws_size,
                              hipStream_t stream){
  const float* x   = (const float*)d_in[0];
  const float* ea  = (const float*)d_in[1];
  const float* rx  = (const float*)d_in[2];
  const float* rea = (const float*)d_in[3];
  GatParams g0{ (const float*)d_in[4],  (const float*)d_in[5],  (const float*)d_in[6],
                (const float*)d_in[7],  (const float*)d_in[8],  (const float*)d_in[9],
                (const float*)d_in[10] };
  GatParams g1{ (const float*)d_in[11], (const float*)d_in[12], (const float*)d_in[13],
                (const float*)d_in[14], (const float*)d_in[15], (const float*)d_in[16],
                (const float*)d_in[17] };
  GatParams g2{ (const float*)d_in[18], (const float*)d_in[19], (const float*)d_in[20],
                (const float*)d_in[21], (const float*)d_in[22], (const float*)d_in[23],
                (const float*)d_in[24] };
  const float* lin_W = (const float*)d_in[25]; const float* lin_b = (const float*)d_in[26];
  const float* f1_W  = (const float*)d_in[27]; const float* f1_b  = (const float*)d_in[28];
  const float* f2_W  = (const float*)d_in[29]; const float* f2_b  = (const float*)d_in[30];
  const float* f3_W  = (const float*)d_in[31]; const float* f3_b  = (const float*)d_in[32];
  const float* bilW  = (const float*)d_in[33]; const float* bilb  = (const float*)d_in[34];
  const int* ei  = (const int*)d_in[35];
  const int* rei = (const int*)d_in[37];
  const int* rb  = (const int*)d_in[38];

  const int N  = in_sizes[0] / 16;
  const int E  = in_sizes[1] / 18;
  const int NR = in_sizes[2] / 16;
  const int ER = in_sizes[3] / 18;
  const int R  = out_size;

  float* Wf = (float*)d_ws;
  size_t off = 0;
  auto alloc  = [&](size_t nf){ nf = (nf + 1) & ~(size_t)1; float* p = Wf + off; off += nf; return p; };
  auto alloci = [&](size_t ni){ ni = (ni + 1) & ~(size_t)1; int* p = (int*)(Wf + off); off += ni; return p; };

  // persistent head
  float* y0 = alloc((size_t)R * 400);
  float* y1 = alloc((size_t)R * 200);
  float* y2 = alloc((size_t)R * 100);
  float* y3 = alloc((size_t)R * 100);
  float* xp = alloc(128);
  int* starts = alloci(R + 1);
  const size_t arena = off;

  // ================= rule path =================
  {
    off = arena;
    float* h1 = alloc((size_t)NR * 100);
    float* h2 = alloc((size_t)NR * 200);
    float* xl = alloc((size_t)NR * 200);
    float* xr = alloc((size_t)NR * 200);
    float2* lw = (float2*)alloc((size_t)ER * 2);
    float* eam   = alloc((size_t)NR * 18);
    float* selfl = alloc(NR);
    int* rowoff = alloci(NR + 1);
    int* degi   = alloci(NR);
    int* pos    = alloci(NR);
    int* bsum   = alloci(128);
    int* eidx   = alloci(ER);
    const int* rsrc = rei; const int* rdst = rei + ER;

    hipMemsetAsync(degi, 0, (size_t)NR * 4, stream);
    k_deg<<<nblk(ER), 256, 0, stream>>>(rdst, degi, ER);
    scan_launch(degi, bsum, rowoff, pos, NR, stream);
    k_fill<<<nblk(ER), 256, 0, stream>>>(rdst, pos, eidx, ER);
    k_easum<<<(NR + 3) / 4, 256, 0, stream>>>(rea, rowoff, eidx, eam, NR);

    run_gatv2(rx, 16, 100, NR, rsrc, rdst, rea, ER, g1, h1, 1,
              xl, xr, lw, selfl, eam, rowoff, eidx, stream);
    run_gatv2(h1, 100, 200, NR, rsrc, rdst, rea, ER, g2, h2, 1,
              xl, xr, lw, selfl, eam, rowoff, eidx, stream);

    float* hlin = xl;  // NR*400 floats (xl+xr contiguous)
    gemm_launch(h2, lin_W, lin_b, hlin, NR, 200, 400, 0, stream);

    k_rule_starts<<<(R + 256) / 256, 256, 0, stream>>>(rb, starts, NR, R);
    k_pool_rules<<<nblk((long)R * 400), 256, 0, stream>>>(hlin, starts, y0, R, 400);

    gemm_launch(y0, f1_W, f1_b, y1, R, 400, 200, 1, stream);
    gemm_launch(y1, f2_W, f2_b, y2, R, 200, 100, 1, stream);
    gemm_launch(y2, f3_W, f3_b, y3, R, 100, 100, 0, stream);
  }

  // ================= data path =================
  {
    off = arena;
    float* g  = alloc((size_t)N * 100);
    float* xl = alloc((size_t)N * 100);
    float* xr = alloc((size_t)N * 100);
    float2* lw = (float2*)alloc((size_t)E * 2);
    float* eam   = alloc((size_t)N * 18);
    float* selfl = alloc(N);
    int* rowoff = alloci((size_t)N + 1);
    int* degi   = alloci(N);
    int* pos    = alloci(N);
    int* bsum   = alloci(128);
    int* eidx   = alloci(E);
    const int* srcp = ei; const int* dstp = ei + E;

    hipMemsetAsync(degi, 0, (size_t)N * 4, stream);
    k_deg<<<nblk(E), 256, 0, stream>>>(dstp, degi, E);
    scan_launch(degi, bsum, rowoff, pos, N, stream);
    k_fill<<<nblk(E), 256, 0, stream>>>(dstp, pos, eidx, E);
    k_easum<<<(N + 3) / 4, 256, 0, stream>>>(ea, rowoff, eidx, eam, N);

    run_gatv2(x, 16, 100, N, srcp, dstp, ea, E, g0, g, 0,
              xl, xr, lw, selfl, eam, rowoff, eidx, stream);

    hipMemsetAsync(xp, 0, 128 * 4, stream);
    k_pool_all<<<1024, 256, 0, stream>>>(g, xp, N, 100);
    k_bil<<<1, 512, 0, stream>>>(xp, bilW, y3, bilb, (float*)d_out, 1.0f / (float)N, R);
  }
}

// Round 10
// 1032.319 us; speedup vs baseline: 2.5837x; 1.0812x over previous
//
#include <hip/hip_runtime.h>

#define NS 0.2f  // leaky_relu negative slope

// ===================== CSR construction =====================
__global__ void k_deg(const int* __restrict__ dst, int* degi, int E){
  int stride = gridDim.x * blockDim.x;
  for(int e = blockIdx.x * blockDim.x + threadIdx.x; e < E; e += stride)
    atomicAdd(&degi[dst[e]], 1);
}

__device__ __forceinline__ int wave_iscan(int v, int lane){
  #pragma unroll
  for(int o = 1; o < 64; o <<= 1){
    int t = __shfl_up(v, o);
    if(lane >= o) v += t;
  }
  return v;
}

// ---- 3-phase multi-block exclusive scan ----
__global__ __launch_bounds__(1024) void k_scan_sum(
    const int* __restrict__ deg, int* __restrict__ bsum, int n)
{
  __shared__ int wsum[16];
  const int lane = threadIdx.x & 63;
  const int w = threadIdx.x >> 6;
  int idx = blockIdx.x * 1024 + threadIdx.x;
  int v = (idx < n) ? deg[idx] : 0;
  #pragma unroll
  for(int o = 32; o; o >>= 1) v += __shfl_xor(v, o);
  if(lane == 0) wsum[w] = v;
  __syncthreads();
  if(w == 0){
    int s = (lane < 16) ? wsum[lane] : 0;
    #pragma unroll
    for(int o = 8; o; o >>= 1) s += __shfl_xor(s, o);
    if(lane == 0) bsum[blockIdx.x] = s;
  }
}

__global__ __launch_bounds__(128) void k_scan_bsum(
    int* __restrict__ bsum, int* __restrict__ rowoff, int B, int n)
{
  __shared__ int wtot[2];
  const int lane = threadIdx.x & 63;
  const int w = threadIdx.x >> 6;
  int t = threadIdx.x;
  int v = (t < B) ? bsum[t] : 0;
  int inc = wave_iscan(v, lane);
  if(lane == 63) wtot[w] = inc;
  __syncthreads();
  int off = (w > 0) ? wtot[0] : 0;
  if(t < B) bsum[t] = off + inc - v;   // exclusive
  if(t == 0) rowoff[n] = wtot[0] + wtot[1];
}

__global__ __launch_bounds__(1024) void k_scan_apply(
    const int* __restrict__ deg, const int* __restrict__ bsum,
    int* __restrict__ rowoff, int* __restrict__ pos, int n)
{
  __shared__ int wsum[16];
  const int lane = threadIdx.x & 63;
  const int w = threadIdx.x >> 6;
  int idx = blockIdx.x * 1024 + threadIdx.x;
  int v = (idx < n) ? deg[idx] : 0;
  int inc = wave_iscan(v, lane);
  if(lane == 63) wsum[w] = inc;
  __syncthreads();
  if(w == 0){
    int s = (lane < 16) ? wsum[lane] : 0;
    s = wave_iscan(s, lane);
    if(lane < 16) wsum[lane] = s;
  }
  __syncthreads();
  int woff = (w > 0) ? wsum[w - 1] : 0;
  if(idx < n){
    int ex = bsum[blockIdx.x] + woff + inc - v;
    rowoff[idx] = ex;
    pos[idx] = ex;
  }
}

__global__ void k_fill(const int* __restrict__ dst, int* pos, int* eidx, int E){
  int stride = gridDim.x * blockDim.x;
  for(int e = blockIdx.x * blockDim.x + threadIdx.x; e < E; e += stride){
    int slot = atomicAdd(&pos[dst[e]], 1);
    eidx[slot] = e;
  }
}

// ===================== ea_mean per node (lane-parallel) =====================
__global__ __launch_bounds__(256) void k_easum(
    const float* __restrict__ ea, const int* __restrict__ rowoff,
    const int* __restrict__ eidx, float* __restrict__ eam, int n)
{
  const int lane = threadIdx.x & 63;
  const int wid  = threadIdx.x >> 6;
  const int i = blockIdx.x * 4 + wid;
  if(i >= n) return;
  const int r0 = rowoff[i], r1 = rowoff[i + 1];
  const int deg = r1 - r0;
  const int pg = lane / 18;          // 0..3 (group 3 idle)
  const int k  = lane - pg * 18;
  float s = 0.0f;
  if(pg < 3){
    for(int p = r0 + pg; p < r1; p += 3)
      s += ea[(long)eidx[p] * 18 + k];
  }
  float b = __shfl(s, lane + 18);
  float c = __shfl(s, lane + 36);
  if(lane < 18) eam[(long)i * 18 + lane] = (s + b + c) / fmaxf((float)deg, 1.0f);
}

// ===================== tiled GEMM: C = A @ W^T + b (k-major LDS, float4 reads) =====================
#define BM 64
#define BN 64
#define BK 16
__global__ __launch_bounds__(256) void k_gemm(
    const float* __restrict__ A, const float* __restrict__ W,
    const float* __restrict__ b, float* __restrict__ C,
    int n, int K, int M, int dorelu)
{
  // k-major tiles: read in k-loop = one ds_read_b128 per operand
  // (+4 pad keeps float4 alignment (272B rows) and bank-stride 4 on staging: 2-way, free)
  __shared__ float As[BK][BM + 4];
  __shared__ float Bs[BK][BN + 4];
  const int bi = blockIdx.x * BM;
  const int bj = blockIdx.y * BN;
  const int tid = threadIdx.x;
  const int tr = tid / 16, tc = tid % 16;
  float acc[4][4] = {};
  for(int k0 = 0; k0 < K; k0 += BK){
    for(int l = tid; l < BM * BK; l += 256){
      int c = l % BK, r = l / BK;          // c fast -> coalesced global read
      int gr = bi + r, gc = k0 + c;
      As[c][r] = (gr < n && gc < K) ? A[(long)gr * K + gc] : 0.0f;
    }
    for(int l = tid; l < BN * BK; l += 256){
      int c = l % BK, r = l / BK;
      int gr = bj + r, gc = k0 + c;
      Bs[c][r] = (gr < M && gc < K) ? W[(long)gr * K + gc] : 0.0f;
    }
    __syncthreads();
    #pragma unroll
    for(int kk = 0; kk < BK; ++kk){
      float4 av = *(const float4*)&As[kk][tr * 4];
      float4 bv = *(const float4*)&Bs[kk][tc * 4];
      acc[0][0] = fmaf(av.x, bv.x, acc[0][0]); acc[0][1] = fmaf(av.x, bv.y, acc[0][1]);
      acc[0][2] = fmaf(av.x, bv.z, acc[0][2]); acc[0][3] = fmaf(av.x, bv.w, acc[0][3]);
      acc[1][0] = fmaf(av.y, bv.x, acc[1][0]); acc[1][1] = fmaf(av.y, bv.y, acc[1][1]);
      acc[1][2] = fmaf(av.y, bv.z, acc[1][2]); acc[1][3] = fmaf(av.y, bv.w, acc[1][3]);
      acc[2][0] = fmaf(av.z, bv.x, acc[2][0]); acc[2][1] = fmaf(av.z, bv.y, acc[2][1]);
      acc[2][2] = fmaf(av.z, bv.z, acc[2][2]); acc[2][3] = fmaf(av.z, bv.w, acc[2][3]);
      acc[3][0] = fmaf(av.w, bv.x, acc[3][0]); acc[3][1] = fmaf(av.w, bv.y, acc[3][1]);
      acc[3][2] = fmaf(av.w, bv.z, acc[3][2]); acc[3][3] = fmaf(av.w, bv.w, acc[3][3]);
    }
    __syncthreads();
  }
  for(int r = 0; r < 4; r++){
    int gr = bi + tr * 4 + r;
    if(gr >= n) continue;
    for(int c = 0; c < 4; c++){
      int gc = bj + tc * 4 + c;
      if(gc >= M) continue;
      float val = acc[r][c] + b[gc];
      C[(long)gr * M + gc] = dorelu ? fmaxf(val, 0.0f) : val;
    }
  }
}

static void gemm_launch(const float* A, const float* W, const float* b, float* C,
                        int n, int K, int M, int relu, hipStream_t s){
  dim3 grid((n + BM - 1) / BM, (M + BN - 1) / BN);
  k_gemm<<<grid, 256, 0, s>>>(A, W, b, C, n, K, M, relu);
}

__device__ __forceinline__ float lkrelu(float t){ return (t > 0.0f) ? t : NS * t; }

// ===================== edge logits: G-lane group x NE=4 edges, persistent blocks =====================
template<int G, int F>
__global__ __launch_bounds__(256) void k_edge_logits(
    const float* __restrict__ xl, const float* __restrict__ xr,
    const float* __restrict__ ea,
    const int* __restrict__ src, const int* __restrict__ dst,
    const int* __restrict__ eidx,
    const float* __restrict__ We, const float* __restrict__ att,
    float2* __restrict__ lw, int E)
{
  constexpr int NG = 256 / G;       // groups per block
  constexpr int NE = 4;             // edges per group-iteration
  constexpr int FQ = F / 4;         // float4s per feature row
  __shared__ float4 sWeT[18 * FQ];  // [k][f4], transposed
  __shared__ float4 sAtt[FQ];
  __shared__ float4 sEa[NG][18];    // [k] -> (ea_e0, ea_e1, ea_e2, ea_e3)
  __shared__ int    sIdx[NG][3][NE];// [0]=e, [1]=src, [2]=dst

  const int tid = threadIdx.x;
  for(int idx = tid; idx < F * 18; idx += 256){
    int f = idx / 18, k = idx % 18;            // coalesced global read
    ((float*)sWeT)[k * F + f] = We[idx];
  }
  for(int f = tid; f < F; f += 256) ((float*)sAtt)[f] = att[f];
  __syncthreads();

  const int g  = tid / G;
  const int gl = tid % G;
  const bool act = (gl * 4 < F);
  const int glc = act ? gl : 0;
  const long step = (long)gridDim.x * (NG * NE);

  for(long base = (long)blockIdx.x * (NG * NE); base < (long)E; base += step){
    const long pb = base + (long)g * NE;
    if(gl < NE){
      long p = pb + gl;
      int e = -1, s = 0, d = 0;
      if(p < (long)E){ e = eidx[p]; s = src[e]; d = dst[e]; }
      sIdx[g][0][gl] = e; sIdx[g][1][gl] = s; sIdx[g][2][gl] = d;
    }
    // stage 4 ea rows as float2 (72B rows are 8B-aligned)
    #pragma unroll
    for(int t = 0; t < (9 * NE + G - 1) / G; ++t){
      int u = t * G + gl;
      if(u < 9 * NE){
        int ne = u & 3, k2 = u >> 2;
        int e = sIdx[g][0][ne];
        float2 v = (e >= 0) ? *(const float2*)(ea + (long)e * 18 + k2 * 2)
                            : make_float2(0.0f, 0.0f);
        ((float*)&sEa[g][k2 * 2 + 0])[ne] = v.x;
        ((float*)&sEa[g][k2 * 2 + 1])[ne] = v.y;
      }
    }
    int4 sv = *(const int4*)&sIdx[g][1][0];
    int4 dv = *(const int4*)&sIdx[g][2][0];
    float4 a0 = *(const float4*)(xl + (long)sv.x * F + glc * 4);
    float4 b0 = *(const float4*)(xr + (long)dv.x * F + glc * 4);
    float4 a1 = *(const float4*)(xl + (long)sv.y * F + glc * 4);
    float4 b1 = *(const float4*)(xr + (long)dv.y * F + glc * 4);
    float4 a2 = *(const float4*)(xl + (long)sv.z * F + glc * 4);
    float4 b2 = *(const float4*)(xr + (long)dv.z * F + glc * 4);
    float4 a3 = *(const float4*)(xl + (long)sv.w * F + glc * 4);
    float4 b3 = *(const float4*)(xr + (long)dv.w * F + glc * 4);
    float4 t0 = make_float4(a0.x + b0.x, a0.y + b0.y, a0.z + b0.z, a0.w + b0.w);
    float4 t1 = make_float4(a1.x + b1.x, a1.y + b1.y, a1.z + b1.z, a1.w + b1.w);
    float4 t2 = make_float4(a2.x + b2.x, a2.y + b2.y, a2.z + b2.z, a2.w + b2.w);
    float4 t3 = make_float4(a3.x + b3.x, a3.y + b3.y, a3.z + b3.z, a3.w + b3.w);
    #pragma unroll
    for(int k = 0; k < 18; ++k){
      float4 w  = sWeT[k * FQ + glc];
      float4 eq = sEa[g][k];
      t0.x = fmaf(w.x, eq.x, t0.x); t0.y = fmaf(w.y, eq.x, t0.y);
      t0.z = fmaf(w.z, eq.x, t0.z); t0.w = fmaf(w.w, eq.x, t0.w);
      t1.x = fmaf(w.x, eq.y, t1.x); t1.y = fmaf(w.y, eq.y, t1.y);
      t1.z = fmaf(w.z, eq.y, t1.z); t1.w = fmaf(w.w, eq.y, t1.w);
      t2.x = fmaf(w.x, eq.z, t2.x); t2.y = fmaf(w.y, eq.z, t2.y);
      t2.z = fmaf(w.z, eq.z, t2.z); t2.w = fmaf(w.w, eq.z, t2.w);
      t3.x = fmaf(w.x, eq.w, t3.x); t3.y = fmaf(w.y, eq.w, t3.y);
      t3.z = fmaf(w.z, eq.w, t3.z); t3.w = fmaf(w.w, eq.w, t3.w);
    }
    float4 av = sAtt[glc];
    float r0 = 0, r1 = 0, r2 = 0, r3 = 0;
    if(act){
      r0 = av.x * lkrelu(t0.x) + av.y * lkrelu(t0.y) + av.z * lkrelu(t0.z) + av.w * lkrelu(t0.w);
      r1 = av.x * lkrelu(t1.x) + av.y * lkrelu(t1.y) + av.z * lkrelu(t1.z) + av.w * lkrelu(t1.w);
      r2 = av.x * lkrelu(t2.x) + av.y * lkrelu(t2.y) + av.z * lkrelu(t2.z) + av.w * lkrelu(t2.w);
      r3 = av.x * lkrelu(t3.x) + av.y * lkrelu(t3.y) + av.z * lkrelu(t3.z) + av.w * lkrelu(t3.w);
    }
    #pragma unroll
    for(int o = G / 2; o; o >>= 1){
      r0 += __shfl_xor(r0, o);
      r1 += __shfl_xor(r1, o);
      r2 += __shfl_xor(r2, o);
      r3 += __shfl_xor(r3, o);
    }
    if(gl == 0 && pb + 0 < (long)E) lw[pb + 0] = make_float2(r0, __int_as_float(sv.x));
    if(gl == 1 && pb + 1 < (long)E) lw[pb + 1] = make_float2(r1, __int_as_float(sv.y));
    if(gl == 2 && pb + 2 < (long)E) lw[pb + 2] = make_float2(r2, __int_as_float(sv.z));
    if(gl == 3 && pb + 3 < (long)E) lw[pb + 3] = make_float2(r3, __int_as_float(sv.w));
  }
}

// ===================== node softmax + aggregate (self-logit fused inline) =====================
#define CH 128
template<int JMAX>
__global__ __launch_bounds__(256) void k_gat_agg(
    const float* __restrict__ xl, const float* __restrict__ xr,
    const float* __restrict__ eam,
    const float* __restrict__ We, const float* __restrict__ att,
    const int* __restrict__ rowoff, const float2* __restrict__ lw,
    const float* __restrict__ bias, float* __restrict__ out,
    int n, int F, int dorelu)
{
  const int lane = threadIdx.x & 63;
  const int wid  = threadIdx.x >> 6;
  __shared__ float2 s_ws[4][CH];   // {weight, src bits}
  const int i = blockIdx.x * 4 + wid;
  if(i >= n) return;          // wave-uniform exit; no __syncthreads below
  const int r0 = rowoff[i], r1 = rowoff[i + 1];
  const int deg = r1 - r0;

  // ---- eam row (wave-uniform scalar loads) ----
  float eamv[18];
  #pragma unroll
  for(int k = 0; k < 18; ++k) eamv[k] = eam[(long)i * 18 + k];

  // ---- self logit (feature-parallel) + acc init from xl[i] ----
  float selfl = 0.0f;
  float acc[JMAX];
  #pragma unroll
  for(int j = 0; j < JMAX; ++j){
    int f = lane + j * 64;
    float xv = (f < F) ? xl[(long)i * F + f] : 0.0f;
    acc[j] = xv;
    if(f < F){
      float t = xv + xr[(long)i * F + f];
      const float* w = We + f * 18;
      #pragma unroll
      for(int k = 0; k < 18; ++k) t = fmaf(w[k], eamv[k], t);
      t = lkrelu(t);
      selfl = fmaf(att[f], t, selfl);
    }
  }
  #pragma unroll
  for(int o = 32; o; o >>= 1) selfl += __shfl_xor(selfl, o);

  float m = selfl, denom = 1.0f;

  for(int c0 = 0; c0 < deg; c0 += CH){
    int cn = min(CH, deg - c0);
    float lmax = -3.4e38f;
    for(int q = lane; q < cn; q += 64){
      float2 ws = lw[r0 + c0 + q];
      s_ws[wid][q] = ws;
      lmax = fmaxf(lmax, ws.x);
    }
    #pragma unroll
    for(int o = 32; o; o >>= 1) lmax = fmaxf(lmax, __shfl_xor(lmax, o));
    float newm = fmaxf(m, lmax);
    float scale = __expf(m - newm);
    denom *= scale;
    #pragma unroll
    for(int j = 0; j < JMAX; ++j) acc[j] *= scale;
    m = newm;
    float psum = 0.0f;
    for(int q = lane; q < cn; q += 64){
      float2 ws = s_ws[wid][q];
      float w = __expf(ws.x - m);
      s_ws[wid][q].x = w;
      psum += w;
    }
    #pragma unroll
    for(int o = 32; o; o >>= 1) psum += __shfl_xor(psum, o);
    denom += psum;
    // gather-aggregate, 8 edges in flight
    int p = 0;
    for(; p + 8 <= cn; p += 8){
      float2 wv[8];
      const float* xs[8];
      #pragma unroll
      for(int u = 0; u < 8; ++u){
        wv[u] = s_ws[wid][p + u];
        xs[u] = xl + (long)__float_as_int(wv[u].y) * F;
      }
      float vv[8][JMAX];
      #pragma unroll
      for(int u = 0; u < 8; ++u)
        #pragma unroll
        for(int j = 0; j < JMAX; ++j){
          int f = lane + j * 64;
          vv[u][j] = (f < F) ? xs[u][f] : 0.0f;
        }
      #pragma unroll
      for(int u = 0; u < 8; ++u)
        #pragma unroll
        for(int j = 0; j < JMAX; ++j)
          acc[j] = fmaf(wv[u].x, vv[u][j], acc[j]);
    }
    for(; p < cn; ++p){
      float2 ws = s_ws[wid][p];
      const float* xs = xl + (long)__float_as_int(ws.y) * F;
      #pragma unroll
      for(int j = 0; j < JMAX; ++j){
        int f = lane + j * 64;
        if(f < F) acc[j] = fmaf(ws.x, xs[f], acc[j]);
      }
    }
  }

  float inv = 1.0f / denom;
  #pragma unroll
  for(int j = 0; j < JMAX; ++j){
    int f = lane + j * 64;
    if(f < F){
      float o = acc[j] * inv + bias[f];
      out[(long)i * F + f] = dorelu ? fmaxf(o, 0.0f) : o;
    }
  }
}

// ===================== rule pooling (rule_batch sorted) =====================
__global__ void k_rule_starts(const int* __restrict__ rb, int* starts, int NR, int R){
  int r = blockIdx.x * blockDim.x + threadIdx.x;
  if(r > R) return;
  if(r == R){ starts[R] = NR; return; }
  int lo = 0, hi = NR;
  while(lo < hi){ int mid = (lo + hi) >> 1; if(rb[mid] < r) lo = mid + 1; else hi = mid; }
  starts[r] = lo;
}

__global__ void k_pool_rules(const float* __restrict__ h, const int* __restrict__ starts,
                             float* __restrict__ y, int R, int F){
  long idx = (long)blockIdx.x * blockDim.x + threadIdx.x;
  long total = (long)R * F;
  if(idx >= total) return;
  int r = (int)(idx / F);
  int f = (int)(idx % F);
  int s0 = starts[r], s1 = starts[r + 1];
  float a = 0.0f;
  for(int i = s0; i < s1; i++) a += h[(long)i * F + f];
  y[idx] = a / fmaxf((float)(s1 - s0), 1.0f);
}

// ===================== global mean (register accumulate) =====================
__global__ __launch_bounds__(256) void k_pool_all(
    const float* __restrict__ g, float* xp, int n, int F)
{
  const int lane = threadIdx.x & 63;
  const int wid  = threadIdx.x >> 6;
  const int nw   = 4;
  float a0 = 0.0f, a1 = 0.0f;
  const bool ok0 = lane < F, ok1 = lane + 64 < F;
  for(int r = blockIdx.x * nw + wid; r < n; r += gridDim.x * nw){
    const float* row = g + (long)r * F;
    if(ok0) a0 += row[lane];
    if(ok1) a1 += row[lane + 64];
  }
  __shared__ float s[4][128];
  s[wid][lane] = a0;
  s[wid][lane + 64] = a1;
  __syncthreads();
  if(wid == 0){
    float t0 = s[0][lane] + s[1][lane] + s[2][lane] + s[3][lane];
    float t1 = s[0][lane + 64] + s[1][lane + 64] + s[2][lane + 64] + s[3][lane + 64];
    if(ok0 && t0 != 0.0f) atomicAdd(&xp[lane], t0);
    if(ok1 && t1 != 0.0f) atomicAdd(&xp[lane + 64], t1);
  }
}

// ===================== fused bilinear head =====================
__global__ __launch_bounds__(512) void k_bil(
    const float* __restrict__ xp, const float* __restrict__ Wb,
    const float* __restrict__ y, const float* __restrict__ bilb,
    float* __restrict__ out, float inv_n, int R)
{
  __shared__ float v[100];
  int t = threadIdx.x;
  if(t < 100){
    float a = 0.0f;
    for(int d = 0; d < 100; d++) a += xp[d] * Wb[d * 100 + t];
    v[t] = a * inv_n;
  }
  __syncthreads();
  for(int r = t; r < R; r += 512){
    float a = 0.0f;
    const float* yr = y + (long)r * 100;
    for(int e = 0; e < 100; e++) a += v[e] * yr[e];
    out[r] = a + bilb[0];
  }
}

// ------------------------------------------------------------------
static inline int nblk(long n){
  long b = (n + 255) / 256;
  if(b > 20480) b = 20480;
  if(b < 1) b = 1;
  return (int)b;
}

struct GatParams { const float *Wl,*bl,*Wr,*br,*We,*att,*b; };

template<int G, int F>
static void logits_launch(const float* xl, const float* xr, const float* ea,
                          const int* src, const int* dst, const int* eidx,
                          const float* We, const float* att, float2* lw,
                          int E, hipStream_t stream){
  const int epb = (256 / G) * 4;   // edges per block-iteration
  long nb = ((long)E + epb - 1) / epb;
  int grid = (int)(nb < 2048 ? nb : 2048);
  k_edge_logits<G, F><<<grid, 256, 0, stream>>>(xl, xr, ea, src, dst, eidx, We, att, lw, E);
}

static void scan_launch(const int* degi, int* bsum, int* rowoff, int* pos,
                        int n, hipStream_t stream){
  int B = (n + 1023) / 1024;
  k_scan_sum  <<<B, 1024, 0, stream>>>(degi, bsum, n);
  k_scan_bsum <<<1, 128,  0, stream>>>(bsum, rowoff, B, n);
  k_scan_apply<<<B, 1024, 0, stream>>>(degi, bsum, rowoff, pos, n);
}

static void run_gatv2(const float* x, int fin, int fout, int n,
                      const int* src, const int* dst, const float* ea, int E,
                      GatParams P, float* out, int dorelu,
                      float* xl, float* xr, float2* lw,
                      const float* eam, const int* rowoff, const int* eidx,
                      hipStream_t stream){
  gemm_launch(x, P.Wl, P.bl, xl, n, fin, fout, 0, stream);
  gemm_launch(x, P.Wr, P.br, xr, n, fin, fout, 0, stream);
  if(fout == 100){
    logits_launch<32, 100>(xl, xr, ea, src, dst, eidx, P.We, P.att, lw, E, stream);
    k_gat_agg<2><<<(n + 3) / 4, 256, 0, stream>>>(xl, xr, eam, P.We, P.att,
                                                  rowoff, lw, P.b, out, n, fout, dorelu);
  } else {
    logits_launch<64, 200>(xl, xr, ea, src, dst, eidx, P.We, P.att, lw, E, stream);
    k_gat_agg<4><<<(n + 3) / 4, 256, 0, stream>>>(xl, xr, eam, P.We, P.att,
                                                  rowoff, lw, P.b, out, n, fout, dorelu);
  }
}

extern "C" void kernel_launch(void* const* d_in, const int* in_sizes, int n_in,
                              void* d_out, int out_size, void* d_ws, size_t ws_size,
                              hipStream_t stream){
  const float* x   = (const float*)d_in[0];
  const float* ea  = (const float*)d_in[1];
  const float* rx  = (const float*)d_in[2];
  const float* rea = (const float*)d_in[3];
  GatParams g0{ (const float*)d_in[4],  (const float*)d_in[5],  (const float*)d_in[6],
                (const float*)d_in[7],  (const float*)d_in[8],  (const float*)d_in[9],
                (const float*)d_in[10] };
  GatParams g1{ (const float*)d_in[11], (const float*)d_in[12], (const float*)d_in[13],
                (const float*)d_in[14], (const float*)d_in[15], (const float*)d_in[16],
                (const float*)d_in[17] };
  GatParams g2{ (const float*)d_in[18], (const float*)d_in[19], (const float*)d_in[20],
                (const float*)d_in[21], (const float*)d_in[22], (const float*)d_in[23],
                (const float*)d_in[24] };
  const float* lin_W = (const float*)d_in[25]; const float* lin_b = (const float*)d_in[26];
  const float* f1_W  = (const float*)d_in[27]; const float* f1_b  = (const float*)d_in[28];
  const float* f2_W  = (const float*)d_in[29]; const float* f2_b  = (const float*)d_in[30];
  const float* f3_W  = (const float*)d_in[31]; const float* f3_b  = (const float*)d_in[32];
  const float* bilW  = (const float*)d_in[33]; const float* bilb  = (const float*)d_in[34];
  const int* ei  = (const int*)d_in[35];
  const int* rei = (const int*)d_in[37];
  const int* rb  = (const int*)d_in[38];

  const int N  = in_sizes[0] / 16;
  const int E  = in_sizes[1] / 18;
  const int NR = in_sizes[2] / 16;
  const int ER = in_sizes[3] / 18;
  const int R  = out_size;

  float* Wf = (float*)d_ws;
  size_t off = 0;
  auto alloc  = [&](size_t nf){ nf = (nf + 1) & ~(size_t)1; float* p = Wf + off; off += nf; return p; };
  auto alloci = [&](size_t ni){ ni = (ni + 1) & ~(size_t)1; int* p = (int*)(Wf + off); off += ni; return p; };

  // persistent head
  float* y0 = alloc((size_t)R * 400);
  float* y1 = alloc((size_t)R * 200);
  float* y2 = alloc((size_t)R * 100);
  float* y3 = alloc((size_t)R * 100);
  float* xp = alloc(128);
  int* starts = alloci(R + 1);
  const size_t arena = off;

  // ================= rule path =================
  {
    off = arena;
    float* h1 = alloc((size_t)NR * 100);
    float* h2 = alloc((size_t)NR * 200);
    float* xl = alloc((size_t)NR * 200);
    float* xr = alloc((size_t)NR * 200);
    float2* lw = (float2*)alloc((size_t)ER * 2);
    float* eam   = alloc((size_t)NR * 18);
    int* rowoff = alloci(NR + 1);
    int* degi   = alloci(NR);
    int* pos    = alloci(NR);
    int* bsum   = alloci(128);
    int* eidx   = alloci(ER);
    const int* rsrc = rei; const int* rdst = rei + ER;

    hipMemsetAsync(degi, 0, (size_t)NR * 4, stream);
    k_deg<<<nblk(ER), 256, 0, stream>>>(rdst, degi, ER);
    scan_launch(degi, bsum, rowoff, pos, NR, stream);
    k_fill<<<nblk(ER), 256, 0, stream>>>(rdst, pos, eidx, ER);
    k_easum<<<(NR + 3) / 4, 256, 0, stream>>>(rea, rowoff, eidx, eam, NR);

    run_gatv2(rx, 16, 100, NR, rsrc, rdst, rea, ER, g1, h1, 1,
              xl, xr, lw, eam, rowoff, eidx, stream);
    run_gatv2(h1, 100, 200, NR, rsrc, rdst, rea, ER, g2, h2, 1,
              xl, xr, lw, eam, rowoff, eidx, stream);

    float* hlin = xl;  // NR*400 floats (xl+xr contiguous)
    gemm_launch(h2, lin_W, lin_b, hlin, NR, 200, 400, 0, stream);

    k_rule_starts<<<(R + 256) / 256, 256, 0, stream>>>(rb, starts, NR, R);
    k_pool_rules<<<nblk((long)R * 400), 256, 0, stream>>>(hlin, starts, y0, R, 400);

    gemm_launch(y0, f1_W, f1_b, y1, R, 400, 200, 1, stream);
    gemm_launch(y1, f2_W, f2_b, y2, R, 200, 100, 1, stream);
    gemm_launch(y2, f3_W, f3_b, y3, R, 100, 100, 0, stream);
  }

  // ================= data path =================
  {
    off = arena;
    float* g  = alloc((size_t)N * 100);
    float* xl = alloc((size_t)N * 100);
    float* xr = alloc((size_t)N * 100);
    float2* lw = (float2*)alloc((size_t)E * 2);
    float* eam   = alloc((size_t)N * 18);
    int* rowoff = alloci((size_t)N + 1);
    int* degi   = alloci(N);
    int* pos    = alloci(N);
    int* bsum   = alloci(128);
    int* eidx   = alloci(E);
    const int* srcp = ei; const int* dstp = ei + E;

    hipMemsetAsync(degi, 0, (size_t)N * 4, stream);
    k_deg<<<nblk(E), 256, 0, stream>>>(dstp, degi, E);
    scan_launch(degi, bsum, rowoff, pos, N, stream);
    k_fill<<<nblk(E), 256, 0, stream>>>(dstp, pos, eidx, E);
    k_easum<<<(N + 3) / 4, 256, 0, stream>>>(ea, rowoff, eidx, eam, N);

    run_gatv2(x, 16, 100, N, srcp, dstp, ea, E, g0, g, 0,
              xl, xr, lw, eam, rowoff, eidx, stream);

    hipMemsetAsync(xp, 0, 128 * 4, stream);
    k_pool_all<<<1024, 256, 0, stream>>>(g, xp, N, 100);
    k_bil<<<1, 512, 0, stream>>>(xp, bilW, y3, bilb, (float*)d_out, 1.0f / (float)N, R);
  }
}